// Round 5
// baseline (1423.817 us; speedup 1.0000x reference)
//
#include <hip/hip_runtime.h>
#include <hip/hip_fp16.h>

// GCN: 4x (gcn_conv + relu) + global mean pool + linear out.
// N=100000 nodes, E=1000000 edges, G=4096 graphs, F_IN=9, H=64.
// R1: wave-per-node gather MLP restructure; layer-4 agg fused with out-proj.
// R2 (FAILED, 237us): global bucket-cursor scatter -- atomic contention.
// R3: scatter-free CSR build (LDS chunk sort + single-writer bucket gather).
// R4: fp16 message rows.  FETCH halved, time flat => NOT byte-bound.
// R5: 8x8 subgroups + persistent waves: 72->63us.  Model across R1/R4/R5:
//     time ~ gather-request count x effective latency; in-flight ~16/CU --
//     throttled by the per-node serial chain (csr -> gather -> reduce).
// R6: edge-centric bucket aggregation, zero per-node chains:
//     - bucket = 64 dst nodes; block owns 64x64 fp32 acc in LDS (stride 65);
//     - init acc with self rows m[n] (sequential), stream packed edges
//       (seq 4B reads), gather m[src] (8 lanes x 16B), LDS atomicAdd;
//     - unroll 4/subgroup => 32 independent gathers in flight per wave;
//     - epilogue: coalesced relu(dis*acc+b) store (or Wout-dot + pool).
//     csr now stores packed (src<<6)|dstoff; agg9 reads src = v>>6.

static inline size_t align256(size_t x){ return (x + 255) & ~size_t(255); }

#define CHUNK 2048          // edges per sort chunk
#define HC    2048          // chunk histogram size (pow2 >= NBK+1)

struct __align__(8)  h4v { __half2 a, b; };        // 4 halves = 8B (lin64 store)
struct __align__(16) h8v { __half2 a, b, c, d; };  // 8 halves = 16B (agg gather)

__global__ void k_zero(int* deg, float* gsum, int* gcount, int N, int G){
  int i = blockIdx.x*blockDim.x + threadIdx.x;
  if (i < N) deg[i] = 0;
  if (i < G){ gsum[i] = 0.f; gcount[i] = 0; }
}

__global__ void k_deg(const int* __restrict__ dst, const int* __restrict__ batch,
                      int* deg, int* gcount, int E, int N){
  int i = blockIdx.x*blockDim.x + threadIdx.x;
  if (i < E) atomicAdd(&deg[dst[i]], 1);
  if (i < N) atomicAdd(&gcount[batch[i]], 1);
}

__global__ void k_scanA(const int* __restrict__ deg, int* blockSums, int N){
  __shared__ int s[256];
  int t = threadIdx.x; int i = blockIdx.x*256 + t;
  s[t] = (i < N) ? deg[i] : 0;
  __syncthreads();
  for (int off=128; off>0; off>>=1){ if (t < off) s[t] += s[t+off]; __syncthreads(); }
  if (t==0) blockSums[blockIdx.x] = s[0];
}

// single-block exclusive scan of up to 512 block sums (NB=391 here)
__global__ void k_scanB(const int* __restrict__ blockSums, int* blockOffs, int NB){
  __shared__ int s[512];
  int t = threadIdx.x;
  int v = (t < NB) ? blockSums[t] : 0;
  s[t] = v; __syncthreads();
  for (int off=1; off<512; off<<=1){
    int add = (t>=off) ? s[t-off] : 0; __syncthreads();
    s[t] += add; __syncthreads();
  }
  if (t < NB) blockOffs[t] = s[t] - v;
}

// exclusive scan -> row_ptr; also dis
__global__ void k_scanC(const int* __restrict__ deg, const int* __restrict__ blockOffs,
                        int* row_ptr, float* dis, int N){
  __shared__ int s[256];
  int t = threadIdx.x; int i = blockIdx.x*256 + t;
  int v = (i < N) ? deg[i] : 0;
  s[t] = v; __syncthreads();
  for (int off=1; off<256; off<<=1){
    int add = (t>=off) ? s[t-off] : 0; __syncthreads();
    s[t] += add; __syncthreads();
  }
  if (i < N){
    int row = blockOffs[blockIdx.x] + s[t] - v;   // exclusive
    row_ptr[i] = row;
    dis[i] = rsqrtf((float)(v + 1));              // +1 self-loop; deg>=1
    if (i == N-1) row_ptr[N] = blockOffs[blockIdx.x] + s[t];
  }
}

// pass 1: sort a 2048-edge chunk by 64-node bucket entirely in LDS, emit the
// sorted image (coalesced) + the chunk's (NBK+1)-entry bucket-offset row.
// Entry packed as (src<<6)|(dst&63); src < 2^17 -> 23 bits, fits.
__global__ __launch_bounds__(256) void k_sortchunk(
    const int* __restrict__ src, const int* __restrict__ dst,
    int* __restrict__ binned, int* __restrict__ hoffC, int E, int NBK){
  __shared__ int hcnt[HC];              // NBK+1 used; padded pow2 for scan
  __shared__ int simg[CHUNK];
  int c = blockIdx.x, t = threadIdx.x;
  int e0 = c*CHUNK;
  int cnt = E - e0; if (cnt > CHUNK) cnt = CHUNK;

  for (int i = t; i < HC; i += 256) hcnt[i] = 0;
  __syncthreads();

  int b_[8], r_[8], v_[8];              // static-indexed (stays in VGPRs)
  #pragma unroll
  for (int j = 0; j < 8; j++){
    int i = t + j*256;
    if (i < cnt){
      int d = dst[e0+i];
      int s = src[e0+i];
      int b = d >> 6;
      b_[j] = b;
      r_[j] = atomicAdd(&hcnt[b], 1);
      v_[j] = (s << 6) | (d & 63);
    } else b_[j] = -1;
  }
  __syncthreads();

  // in-place Hillis-Steele inclusive scan of hcnt[0..HC-1]
  int own[8];
  #pragma unroll
  for (int j = 0; j < 8; j++) own[j] = hcnt[t + j*256];
  for (int off = 1; off < HC; off <<= 1){
    int nv[8];
    #pragma unroll
    for (int j = 0; j < 8; j++){
      int i = t + j*256;
      nv[j] = hcnt[i] + ((i >= off) ? hcnt[i-off] : 0);
    }
    __syncthreads();
    #pragma unroll
    for (int j = 0; j < 8; j++) hcnt[t + j*256] = nv[j];
    __syncthreads();
  }
  // inclusive -> exclusive
  #pragma unroll
  for (int j = 0; j < 8; j++) hcnt[t + j*256] -= own[j];
  __syncthreads();

  // emit bucket-offset row (hcnt[NBK] == cnt since buckets >= NBK are empty)
  for (int i = t; i < NBK+1; i += 256) hoffC[(size_t)c*(NBK+1) + i] = hcnt[i];

  // place edges bucket-major in LDS
  #pragma unroll
  for (int j = 0; j < 8; j++)
    if (b_[j] >= 0) simg[hcnt[b_[j]] + r_[j]] = v_[j];
  __syncthreads();

  // coalesced stream-out of the sorted chunk image
  for (int i = t; i < cnt; i += 256) binned[e0 + i] = simg[i];
}

// pass 2: WG per bucket gathers its segments from every chunk image and writes
// its own csr region (single-writer, full-line writebacks).  Per-node order
// resolved with LDS cursors.  csr entries stay PACKED (src<<6)|dstoff.
__global__ __launch_bounds__(256) void k_gather(
    const int* __restrict__ binned, const int* __restrict__ hoffC,
    const int* __restrict__ row_ptr,
    int* __restrict__ csr, int N, int NC, int NBK){
  __shared__ int lcur[64];
  int b = blockIdx.x, t = threadIdx.x;
  int n0 = b << 6;
  int nn = N - n0; if (nn > 64) nn = 64;
  if (t < nn) lcur[t] = row_ptr[n0 + t];
  __syncthreads();
  for (int c = t; c < NC; c += 256){
    size_t hb = (size_t)c*(NBK+1) + b;
    int o0 = hoffC[hb];
    int o1 = hoffC[hb + 1];
    int base = c*CHUNK;
    for (int k = o0; k < o1; k++){
      int v = binned[base + k];
      int pos = atomicAdd(&lcur[v & 63], 1);
      csr[pos] = v;
    }
  }
}

// xs[n] = x[n] * dis[n]  (premultiply so the gather loop has one load per edge)
__global__ void k_premul(const float* __restrict__ x, const float* __restrict__ dis,
                         float* __restrict__ xs, int N){
  int i = blockIdx.x*blockDim.x + threadIdx.x;
  if (i < N*9) xs[i] = x[i]*dis[i/9];
}

// layer-1 aggregation over xs (9 features): thread per (node, feature).
// csr entries are packed -> src = v >> 6.
__global__ void k_agg9(const float* __restrict__ xs, const float* __restrict__ dis,
                       const int* __restrict__ row_ptr, const int* __restrict__ csr,
                       float* __restrict__ xagg, int N){
  int tid = blockIdx.x*blockDim.x + threadIdx.x;
  if (tid >= N*9) return;
  int n = tid/9, f = tid - n*9;
  float dn = dis[n];
  int s0 = row_ptr[n], s1 = row_ptr[n+1];
  float a0 = xs[tid];                 // self-loop term (x[n]*dis[n])
  float a1 = 0.f, a2 = 0.f, a3 = 0.f;
  int j = s0;
  for (; j + 3 < s1; j += 4){
    int e0 = csr[j]>>6, e1 = csr[j+1]>>6, e2 = csr[j+2]>>6, e3 = csr[j+3]>>6;
    a0 += xs[e0*9+f];
    a1 += xs[e1*9+f];
    a2 += xs[e2*9+f];
    a3 += xs[e3*9+f];
  }
  for (; j < s1; j++) a0 += xs[(csr[j]>>6)*9+f];
  xagg[tid] = ((a0+a1)+(a2+a3))*dn;
}

// h1 = relu(xagg @ W1 + b1)   (9 -> 64)
__global__ void k_lin1(const float* __restrict__ xagg, const float* __restrict__ W1,
                       const float* __restrict__ b1, float* __restrict__ h, int N){
  __shared__ float Wl[576];
  __shared__ float bl[64];
  int t = threadIdx.x;
  for (int i = t; i < 576; i += 256) Wl[i] = W1[i];
  if (t < 64) bl[t] = b1[t];
  __syncthreads();
  int tid = blockIdx.x*256 + t;
  int n = tid >> 6, f = tid & 63;
  if (n >= N) return;
  float acc = bl[f];
  #pragma unroll
  for (int k = 0; k < 9; k++) acc = fmaf(xagg[n*9+k], Wl[k*64+f], acc);
  h[tid] = fmaxf(acc, 0.f);
}

// m[n] = fp16( dis[n] * (h[n] @ W) )   (64 -> 64); 16-node tiles, 4 outs/thread
__global__ __launch_bounds__(256) void k_lin64(
    const float* __restrict__ h, const float* __restrict__ W,
    const float* __restrict__ dis, h4v* __restrict__ m, int N){
  __shared__ __align__(16) float Wl[64*64];
  __shared__ float hl[16*65];          // +1 pad: conflict-free broadcast reads
  int t = threadIdx.x;
  for (int i = t; i < 4096; i += 256) Wl[i] = W[i];
  int tiles = (N + 15) >> 4;
  int nl = t >> 4, q = t & 15;
  const float4* W4 = (const float4*)Wl;
  for (int tile = blockIdx.x; tile < tiles; tile += gridDim.x){
    int n0 = tile << 4;
    __syncthreads();
    #pragma unroll
    for (int j = 0; j < 4; j++){
      int idx = t + j*256;                       // 0..1023 over 16 nodes x 64 feats
      int node = n0 + (idx >> 6);
      float v = (node < N) ? h[n0*64 + idx] : 0.f;
      hl[(idx>>6)*65 + (idx&63)] = v;
    }
    __syncthreads();
    int node = n0 + nl;
    if (node < N){
      float4 acc = {0.f,0.f,0.f,0.f};
      #pragma unroll
      for (int k = 0; k < 64; k++){
        float hv = hl[nl*65 + k];
        float4 w = W4[k*16 + q];
        acc.x = fmaf(hv, w.x, acc.x);
        acc.y = fmaf(hv, w.y, acc.y);
        acc.z = fmaf(hv, w.z, acc.z);
        acc.w = fmaf(hv, w.w, acc.w);
      }
      float s = dis[node];
      h4v o;
      o.a = __floats2half2_rn(acc.x*s, acc.y*s);
      o.b = __floats2half2_rn(acc.z*s, acc.w*s);
      m[n0*16 + t] = o;                 // 8B/thread, coalesced
    }
  }
}

// LDS accumulate of one gathered row fragment (8 feats) into acc[dstoff][*]
#define ADDE(g, v) do{ float* a_ = &acc[((v) & 63)*65 + q2*8];          \
  float2 f0_=__half22float2((g).a), f1_=__half22float2((g).b),          \
         f2_=__half22float2((g).c), f3_=__half22float2((g).d);          \
  atomicAdd(a_+0,f0_.x); atomicAdd(a_+1,f0_.y);                         \
  atomicAdd(a_+2,f1_.x); atomicAdd(a_+3,f1_.y);                         \
  atomicAdd(a_+4,f2_.x); atomicAdd(a_+5,f2_.y);                         \
  atomicAdd(a_+6,f3_.x); atomicAdd(a_+7,f3_.y); }while(0)

// shared body: init acc with self rows, stream packed edges, gather+accumulate
#define AGGE_BODY                                                        \
  int b = blockIdx.x, t = threadIdx.x;                                   \
  int n0 = b << 6;                                                       \
  int nn = N - n0; if (nn > 64) nn = 64;                                 \
  for (int j = 0; j < 2; j++){                                           \
    int c = t + j*256;                                                   \
    int node = c >> 3, p = c & 7;                                        \
    if (node < nn){                                                      \
      h8v v = m[(size_t)(n0+node)*8 + p];                                \
      float2 f0=__half22float2(v.a), f1=__half22float2(v.b);             \
      float2 f2=__half22float2(v.c), f3=__half22float2(v.d);             \
      float* a = &acc[node*65 + p*8];                                    \
      a[0]=f0.x; a[1]=f0.y; a[2]=f1.x; a[3]=f1.y;                        \
      a[4]=f2.x; a[5]=f2.y; a[6]=f3.x; a[7]=f3.y;                        \
    }                                                                    \
  }                                                                      \
  __syncthreads();                                                       \
  int base = row_ptr[n0];                                                \
  int lastn = n0 + 64; if (lastn > N) lastn = N;                         \
  int end = row_ptr[lastn];                                              \
  int wave = t >> 6, lane = t & 63, sub = lane >> 3, q2 = lane & 7;      \
  for (int eb0 = base + wave*32; eb0 < end; eb0 += 128){                 \
    int e0 = eb0 + sub*4;                                                \
    int rem = end - e0;                                                  \
    int v0 = (rem > 0) ? csrp[e0]   : -1;                                \
    int v1 = (rem > 1) ? csrp[e0+1] : -1;                                \
    int v2 = (rem > 2) ? csrp[e0+2] : -1;                                \
    int v3 = (rem > 3) ? csrp[e0+3] : -1;                                \
    h8v g0, g1, g2, g3;                                                  \
    if (v0 >= 0) g0 = m[(size_t)(v0>>6)*8 + q2];                         \
    if (v1 >= 0) g1 = m[(size_t)(v1>>6)*8 + q2];                         \
    if (v2 >= 0) g2 = m[(size_t)(v2>>6)*8 + q2];                         \
    if (v3 >= 0) g3 = m[(size_t)(v3>>6)*8 + q2];                         \
    if (v0 >= 0) ADDE(g0, v0);                                           \
    if (v1 >= 0) ADDE(g1, v1);                                           \
    if (v2 >= 0) ADDE(g2, v2);                                           \
    if (v3 >= 0) ADDE(g3, v3);                                           \
  }                                                                      \
  __syncthreads();

// h'[n] = relu(dis[n]*acc[n] + b)   (acc includes self row)
__global__ __launch_bounds__(256) void k_aggE(
    const h8v* __restrict__ m, const float* __restrict__ dis,
    const float* __restrict__ bias,
    const int* __restrict__ row_ptr, const int* __restrict__ csrp,
    float* __restrict__ h, int N){
  __shared__ float acc[64*65];
  AGGE_BODY
  int node = t >> 2, fq = (t & 3) * 16;
  if (node < nn){
    float dn = dis[n0+node];
    const float4* b4 = (const float4*)bias;
    float4* hrow = (float4*)(h + (size_t)(n0+node)*64);
    #pragma unroll
    for (int j = 0; j < 4; j++){
      float* a = &acc[node*65 + fq + j*4];
      float4 bb = b4[(fq>>2) + j];
      float4 o;
      o.x = fmaxf(fmaf(a[0], dn, bb.x), 0.f);
      o.y = fmaxf(fmaf(a[1], dn, bb.y), 0.f);
      o.z = fmaxf(fmaf(a[2], dn, bb.z), 0.f);
      o.w = fmaxf(fmaf(a[3], dn, bb.w), 0.f);
      hrow[(fq>>2) + j] = o;
    }
  }
}

// layer-4: same accumulate, epilogue fused with output projection + pool
__global__ __launch_bounds__(256) void k_aggE_out(
    const h8v* __restrict__ m, const float* __restrict__ dis,
    const float* __restrict__ bias, const float* __restrict__ Wout,
    const int* __restrict__ batch,
    const int* __restrict__ row_ptr, const int* __restrict__ csrp,
    float* gsum, int N){
  __shared__ float acc[64*65];
  AGGE_BODY
  int node = t >> 2, fq = (t & 3) * 16;
  float p = 0.f;
  if (node < nn){
    float dn = dis[n0+node];
    const float4* b4 = (const float4*)bias;
    const float4* w4 = (const float4*)Wout;
    #pragma unroll
    for (int j = 0; j < 4; j++){
      float* a = &acc[node*65 + fq + j*4];
      float4 bb = b4[(fq>>2) + j];
      float4 ww = w4[(fq>>2) + j];
      p += fmaxf(fmaf(a[0], dn, bb.x), 0.f) * ww.x;
      p += fmaxf(fmaf(a[1], dn, bb.y), 0.f) * ww.y;
      p += fmaxf(fmaf(a[2], dn, bb.z), 0.f) * ww.z;
      p += fmaxf(fmaf(a[3], dn, bb.w), 0.f) * ww.w;
    }
  }
  p += __shfl_xor(p, 1, 64);
  p += __shfl_xor(p, 2, 64);
  if ((t & 3) == 0 && node < nn) atomicAdd(&gsum[batch[n0+node]], p);
}

__global__ void k_final(const float* __restrict__ gsum, const int* __restrict__ gcount,
                        const float* __restrict__ bout, float* __restrict__ out, int G){
  int g = blockIdx.x*blockDim.x + threadIdx.x;
  if (g < G){
    int c = gcount[g];
    out[g] = gsum[g]/(float)(c > 0 ? c : 1) + bout[0];
  }
}

extern "C" void kernel_launch(void* const* d_in, const int* in_sizes, int n_in,
                              void* d_out, int out_size, void* d_ws, size_t ws_size,
                              hipStream_t stream){
  const float* x    = (const float*)d_in[0];
  const int*   ei   = (const int*)d_in[1];
  const int*   batch= (const int*)d_in[2];
  const float* W1 = (const float*)d_in[3];  const float* b1 = (const float*)d_in[4];
  const float* W2 = (const float*)d_in[5];  const float* b2 = (const float*)d_in[6];
  const float* W3 = (const float*)d_in[7];  const float* b3 = (const float*)d_in[8];
  const float* W4 = (const float*)d_in[9];  const float* b4 = (const float*)d_in[10];
  const float* Wout = (const float*)d_in[11]; const float* bout = (const float*)d_in[12];
  float* out = (float*)d_out;

  const int N = in_sizes[0]/9;
  const int E = in_sizes[1]/2;
  const int G = out_size;
  const int* src = ei;        // edge_index[0]
  const int* dst = ei + E;    // edge_index[1]

  char* ws = (char*)d_ws;
  size_t off = 0;
  auto alloc = [&](size_t bytes){ void* p = ws + off; off = align256(off + bytes); return p; };
  int*   deg      = (int*)  alloc((size_t)N*4);
  int*   row_ptr  = (int*)  alloc((size_t)(N+1)*4);
  int*   csr      = (int*)  alloc((size_t)E*4);
  float* dis      = (float*)alloc((size_t)N*4);
  const int NB  = (N + 255)/256;        // 391 (< 512 required by k_scanB)
  const int NBK = (N + 63)/64;          // 1563 buckets of 64 dst nodes
  const int NC  = (E + CHUNK-1)/CHUNK;  // 489 sort chunks
  int*   blockSums= (int*)  alloc((size_t)NB*4);
  int*   blockOffs= (int*)  alloc((size_t)NB*4);
  int*   hoffC    = (int*)  alloc((size_t)NC*(NBK+1)*4); // per-chunk bucket offsets
  float* gsum     = (float*)alloc((size_t)G*4);
  int*   gcount   = (int*)  alloc((size_t)G*4);
  float* bufA     = (float*)alloc((size_t)N*64*4);
  h4v*   mbuf     = (h4v*)  alloc((size_t)N*64*2);   // fp16 message rows (128B)
  float* xagg     = (float*)mbuf;  // layer-1 9-feat aggregate (N*9*4 <= N*128)
  float* xs       = bufA;   // premultiplied x aliases bufA (freed by k_lin1 write)
  int*   binned   = (int*)bufA;  // E*4 = 4MB <= N*64*4; consumed by k_gather
                                 // BEFORE k_premul writes xs into the same region

  const int EN = (E > N) ? E : N;

  k_zero     <<<(N+255)/256, 256, 0, stream>>>(deg, gsum, gcount, N, G);
  k_deg      <<<(EN+255)/256, 256, 0, stream>>>(dst, batch, deg, gcount, E, N);
  k_scanA    <<<NB, 256, 0, stream>>>(deg, blockSums, N);
  k_scanB    <<<1, 512, 0, stream>>>(blockSums, blockOffs, NB);
  k_scanC    <<<NB, 256, 0, stream>>>(deg, blockOffs, row_ptr, dis, N);
  k_sortchunk<<<NC, 256, 0, stream>>>(src, dst, binned, hoffC, E, NBK);
  k_gather   <<<NBK, 256, 0, stream>>>(binned, hoffC, row_ptr, csr, N, NC, NBK);

  // layer 1: premultiply, aggregate (9 feats), then transform
  k_premul<<<(N*9+255)/256, 256, 0, stream>>>(x, dis, xs, N);
  k_agg9  <<<(N*9+255)/256, 256, 0, stream>>>(xs, dis, row_ptr, csr, xagg, N);
  k_lin1  <<<(N*64+255)/256, 256, 0, stream>>>(xagg, W1, b1, bufA, N);

  // layers 2-3: transform (with dis premult, fp16 store) then aggregate
  const float* Ws[2] = {W2, W3};
  const float* bs[2] = {b2, b3};
  for (int l = 0; l < 2; l++){
    k_lin64<<<1792, 256, 0, stream>>>(bufA, Ws[l], dis, mbuf, N);
    k_aggE <<<NBK, 256, 0, stream>>>((const h8v*)mbuf, dis, bs[l],
                                     row_ptr, csr, bufA, N);
  }

  // layer 4: transform, then aggregation fused with output projection + pool
  k_lin64<<<1792, 256, 0, stream>>>(bufA, W4, dis, mbuf, N);
  k_aggE_out<<<NBK, 256, 0, stream>>>((const h8v*)mbuf, dis, b4, Wout, batch,
                                      row_ptr, csr, gsum, N);

  k_final<<<(G+255)/256, 256, 0, stream>>>(gsum, gcount, bout, out, G);
}

// Round 6
// 451.125 us; speedup vs baseline: 3.1561x; 3.1561x over previous
//
#include <hip/hip_runtime.h>
#include <hip/hip_fp16.h>

// GCN: 4x (gcn_conv + relu) + global mean pool + linear out.
// N=100000 nodes, E=1000000 edges, G=4096 graphs, F_IN=9, H=64.
// R1: wave-per-node gather MLP restructure; layer-4 agg fused with out-proj.
// R2 (FAILED, 237us): global bucket-cursor scatter -- atomic contention.
// R3: scatter-free CSR build (LDS chunk sort + single-writer bucket gather).
// R4: fp16 message rows.  FETCH halved, time flat => NOT byte-bound.
// R5: 8x8 subgroups + persistent waves + row_ptr prefetch: 72->63us/agg.
// R6 (FAILED, 382us/agg): edge-centric LDS-atomic aggregation -- 64M LDS fp32
//     atomics serialized everything (VALUBusy 1.1%).  Register-accumulate +
//     shuffle-reduce (R5) is the right structure on CDNA; REVERTED.
// R7: keep R5 aggregation; move the h@W transform (3x ~45us, LDS-pipe-bound
//     VALU matmul) onto MFMA: v_mfma_f32_16x16x32_f16, A-frags straight from
//     global fp32 h (no LDS), W held as registered fp16 B-frags, epilogue
//     applies dis and stores fp16 m (same layout k_agg64 reads).

static inline size_t align256(size_t x){ return (x + 255) & ~size_t(255); }

#define CHUNK 2048          // edges per sort chunk

struct __align__(8)  h4v { __half2 a, b; };        // 4 halves = 8B
struct __align__(16) h8v { __half2 a, b, c, d; };  // 8 halves = 16B (agg gather)

typedef _Float16 f16x8 __attribute__((ext_vector_type(8)));
typedef float    f32x4 __attribute__((ext_vector_type(4)));

__global__ void k_zero(int* deg, float* gsum, int* gcount, int N, int G){
  int i = blockIdx.x*blockDim.x + threadIdx.x;
  if (i < N) deg[i] = 0;
  if (i < G){ gsum[i] = 0.f; gcount[i] = 0; }
}

__global__ void k_deg(const int* __restrict__ dst, const int* __restrict__ batch,
                      int* deg, int* gcount, int E, int N){
  int i = blockIdx.x*blockDim.x + threadIdx.x;
  if (i < E) atomicAdd(&deg[dst[i]], 1);
  if (i < N) atomicAdd(&gcount[batch[i]], 1);
}

__global__ void k_scanA(const int* __restrict__ deg, int* blockSums, int N){
  __shared__ int s[256];
  int t = threadIdx.x; int i = blockIdx.x*256 + t;
  s[t] = (i < N) ? deg[i] : 0;
  __syncthreads();
  for (int off=128; off>0; off>>=1){ if (t < off) s[t] += s[t+off]; __syncthreads(); }
  if (t==0) blockSums[blockIdx.x] = s[0];
}

// single-block exclusive scan of up to 512 block sums (NB=391 here)
__global__ void k_scanB(const int* __restrict__ blockSums, int* blockOffs, int NB){
  __shared__ int s[512];
  int t = threadIdx.x;
  int v = (t < NB) ? blockSums[t] : 0;
  s[t] = v; __syncthreads();
  for (int off=1; off<512; off<<=1){
    int add = (t>=off) ? s[t-off] : 0; __syncthreads();
    s[t] += add; __syncthreads();
  }
  if (t < NB) blockOffs[t] = s[t] - v;
}

// exclusive scan -> row_ptr; also dis
__global__ void k_scanC(const int* __restrict__ deg, const int* __restrict__ blockOffs,
                        int* row_ptr, float* dis, int N){
  __shared__ int s[256];
  int t = threadIdx.x; int i = blockIdx.x*256 + t;
  int v = (i < N) ? deg[i] : 0;
  s[t] = v; __syncthreads();
  for (int off=1; off<256; off<<=1){
    int add = (t>=off) ? s[t-off] : 0; __syncthreads();
    s[t] += add; __syncthreads();
  }
  if (i < N){
    int row = blockOffs[blockIdx.x] + s[t] - v;   // exclusive
    row_ptr[i] = row;
    dis[i] = rsqrtf((float)(v + 1));              // +1 self-loop; deg>=1
    if (i == N-1) row_ptr[N] = blockOffs[blockIdx.x] + s[t];
  }
}

// pass 1: sort a 2048-edge chunk by bucket entirely in LDS, emit the sorted
// image (coalesced) + the chunk's 783-entry bucket-offset row (coalesced).
// Entry packed as (src<<7)|(dst&127); src < 2^17 fits.
__global__ __launch_bounds__(256) void k_sortchunk(
    const int* __restrict__ src, const int* __restrict__ dst,
    int* __restrict__ binned, int* __restrict__ hoffC, int E){
  __shared__ int hcnt[1024];            // 782 used; padded pow2 for scan
  __shared__ int simg[CHUNK];
  int c = blockIdx.x, t = threadIdx.x;
  int e0 = c*CHUNK;
  int cnt = E - e0; if (cnt > CHUNK) cnt = CHUNK;

  for (int i = t; i < 1024; i += 256) hcnt[i] = 0;
  __syncthreads();

  int b_[8], r_[8], v_[8];              // static-indexed (stays in VGPRs)
  #pragma unroll
  for (int j = 0; j < 8; j++){
    int i = t + j*256;
    if (i < cnt){
      int d = dst[e0+i];
      int s = src[e0+i];
      int b = d >> 7;
      b_[j] = b;
      r_[j] = atomicAdd(&hcnt[b], 1);
      v_[j] = (s << 7) | (d & 127);
    } else b_[j] = -1;
  }
  __syncthreads();

  // in-place Hillis-Steele inclusive scan of hcnt[0..1023]
  int own[4];
  #pragma unroll
  for (int j = 0; j < 4; j++) own[j] = hcnt[t + j*256];
  for (int off = 1; off < 1024; off <<= 1){
    int nv[4];
    #pragma unroll
    for (int j = 0; j < 4; j++){
      int i = t + j*256;
      nv[j] = hcnt[i] + ((i >= off) ? hcnt[i-off] : 0);
    }
    __syncthreads();
    #pragma unroll
    for (int j = 0; j < 4; j++) hcnt[t + j*256] = nv[j];
    __syncthreads();
  }
  // inclusive -> exclusive
  #pragma unroll
  for (int j = 0; j < 4; j++) hcnt[t + j*256] -= own[j];
  __syncthreads();

  // emit bucket-offset row (hcnt[782] == cnt since buckets >=782 are empty)
  for (int i = t; i < 783; i += 256) hoffC[c*783 + i] = hcnt[i];

  // place edges bucket-major in LDS
  #pragma unroll
  for (int j = 0; j < 8; j++)
    if (b_[j] >= 0) simg[hcnt[b_[j]] + r_[j]] = v_[j];
  __syncthreads();

  // coalesced stream-out of the sorted chunk image
  for (int i = t; i < cnt; i += 256) binned[e0 + i] = simg[i];
}

// pass 2: WG per bucket gathers its segments from every chunk image and writes
// its own csr region (single-writer, full-line writebacks).  Per-node order
// resolved with LDS cursors.
__global__ __launch_bounds__(256) void k_gather(
    const int* __restrict__ binned, const int* __restrict__ hoffC,
    const int* __restrict__ row_ptr,
    int* __restrict__ csr, int N, int NC){
  __shared__ int lcur[128];
  int b = blockIdx.x, t = threadIdx.x;
  int n0 = b << 7;
  int nn = N - n0; if (nn > 128) nn = 128;
  if (t < nn) lcur[t] = row_ptr[n0 + t];
  __syncthreads();
  for (int c = t; c < NC; c += 256){
    int o0 = hoffC[c*783 + b];
    int o1 = hoffC[c*783 + b + 1];
    int base = c*CHUNK;
    for (int k = o0; k < o1; k++){
      int v = binned[base + k];
      int pos = atomicAdd(&lcur[v & 127], 1);
      csr[pos] = v >> 7;
    }
  }
}

// xs[n] = x[n] * dis[n]  (premultiply so the gather loop has one load per edge)
__global__ void k_premul(const float* __restrict__ x, const float* __restrict__ dis,
                         float* __restrict__ xs, int N){
  int i = blockIdx.x*blockDim.x + threadIdx.x;
  if (i < N*9) xs[i] = x[i]*dis[i/9];
}

// layer-1 aggregation over xs (9 features): thread per (node, feature), unroll-4 MLP
__global__ void k_agg9(const float* __restrict__ xs, const float* __restrict__ dis,
                       const int* __restrict__ row_ptr, const int* __restrict__ csr,
                       float* __restrict__ xagg, int N){
  int tid = blockIdx.x*blockDim.x + threadIdx.x;
  if (tid >= N*9) return;
  int n = tid/9, f = tid - n*9;
  float dn = dis[n];
  int s0 = row_ptr[n], s1 = row_ptr[n+1];
  float a0 = xs[tid];                 // self-loop term (x[n]*dis[n])
  float a1 = 0.f, a2 = 0.f, a3 = 0.f;
  int j = s0;
  for (; j + 3 < s1; j += 4){
    int e0 = csr[j], e1 = csr[j+1], e2 = csr[j+2], e3 = csr[j+3];
    a0 += xs[e0*9+f];
    a1 += xs[e1*9+f];
    a2 += xs[e2*9+f];
    a3 += xs[e3*9+f];
  }
  for (; j < s1; j++) a0 += xs[csr[j]*9+f];
  xagg[tid] = ((a0+a1)+(a2+a3))*dn;
}

// h1 = relu(xagg @ W1 + b1)   (9 -> 64)
__global__ void k_lin1(const float* __restrict__ xagg, const float* __restrict__ W1,
                       const float* __restrict__ b1, float* __restrict__ h, int N){
  __shared__ float Wl[576];
  __shared__ float bl[64];
  int t = threadIdx.x;
  for (int i = t; i < 576; i += 256) Wl[i] = W1[i];
  if (t < 64) bl[t] = b1[t];
  __syncthreads();
  int tid = blockIdx.x*256 + t;
  int n = tid >> 6, f = tid & 63;
  if (n >= N) return;
  float acc = bl[f];
  #pragma unroll
  for (int k = 0; k < 9; k++) acc = fmaf(xagg[n*9+k], Wl[k*64+f], acc);
  h[tid] = fmaxf(acc, 0.f);
}

// m[n] = fp16( dis[n] * (h[n] @ W) )  via v_mfma_f32_16x16x32_f16.
// Fragment layouts (gfx950):
//   A (16x32): lane l, reg j -> A[l&15][(l>>4)*8 + j]
//   B (32x16): lane l, reg j -> B[(l>>4)*8 + j][l&15]
//   D (16x16): lane l, reg j -> D[(l>>4)*4 + j][l&15]
// A loaded straight from fp32 h (4x float4/lane, no LDS); W held as fp16
// B-frags in registers (one-time per wave); persistent tile loop.
__global__ __launch_bounds__(256) void k_lin64_mfma(
    const float* __restrict__ h, const float* __restrict__ W,
    const float* __restrict__ dis, __half* __restrict__ m, int N){
  int t = threadIdx.x;
  int wid = (blockIdx.x*blockDim.x + t) >> 6;
  int nwaves = (gridDim.x*blockDim.x) >> 6;
  int lane = t & 63;
  int lm = lane & 15, lk = lane >> 4;

  // B fragments: 4 f-tiles x 2 k-halves
  f16x8 bf[4][2];
  #pragma unroll
  for (int ft = 0; ft < 4; ft++){
    #pragma unroll
    for (int kb = 0; kb < 2; kb++){
      int kbase = kb*32 + lk*8;
      #pragma unroll
      for (int j = 0; j < 8; j++)
        bf[ft][kb][j] = (_Float16)W[(kbase + j)*64 + ft*16 + lm];
    }
  }

  int tiles = (N + 15) >> 4;
  for (int tile = wid; tile < tiles; tile += nwaves){
    int n0 = tile << 4;
    int arow = n0 + lm;
    bool rowok = (arow < N);
    const float* hr = h + (size_t)arow*64;
    float4 z = make_float4(0.f,0.f,0.f,0.f);
    float4 x0 = rowok ? *(const float4*)(hr + lk*8)          : z;
    float4 x1 = rowok ? *(const float4*)(hr + lk*8 + 4)      : z;
    float4 x2 = rowok ? *(const float4*)(hr + 32 + lk*8)     : z;
    float4 x3 = rowok ? *(const float4*)(hr + 32 + lk*8 + 4) : z;
    f16x8 a0, a1;
    a0[0]=(_Float16)x0.x; a0[1]=(_Float16)x0.y; a0[2]=(_Float16)x0.z; a0[3]=(_Float16)x0.w;
    a0[4]=(_Float16)x1.x; a0[5]=(_Float16)x1.y; a0[6]=(_Float16)x1.z; a0[7]=(_Float16)x1.w;
    a1[0]=(_Float16)x2.x; a1[1]=(_Float16)x2.y; a1[2]=(_Float16)x2.z; a1[3]=(_Float16)x2.w;
    a1[4]=(_Float16)x3.x; a1[5]=(_Float16)x3.y; a1[6]=(_Float16)x3.z; a1[7]=(_Float16)x3.w;

    float dv[4];
    #pragma unroll
    for (int j = 0; j < 4; j++){
      int r = n0 + lk*4 + j;
      dv[j] = (r < N) ? dis[r] : 0.f;
    }

    #pragma unroll
    for (int ft = 0; ft < 4; ft++){
      f32x4 acc = {0.f, 0.f, 0.f, 0.f};
      acc = __builtin_amdgcn_mfma_f32_16x16x32_f16(a0, bf[ft][0], acc, 0, 0, 0);
      acc = __builtin_amdgcn_mfma_f32_16x16x32_f16(a1, bf[ft][1], acc, 0, 0, 0);
      #pragma unroll
      for (int j = 0; j < 4; j++){
        int r = n0 + lk*4 + j;
        if (r < N) m[(size_t)r*64 + ft*16 + lm] = __float2half(acc[j]*dv[j]);
      }
    }
  }
}

#define ACC8(a)  do{ float2 t_;                                    \
  t_ = __half22float2((a).a); acc0 += t_.x; acc1 += t_.y;          \
  t_ = __half22float2((a).b); acc2 += t_.x; acc3 += t_.y;          \
  t_ = __half22float2((a).c); acc4 += t_.x; acc5 += t_.y;          \
  t_ = __half22float2((a).d); acc6 += t_.x; acc7 += t_.y; }while(0)

#define RED3(v)  do{ v += __shfl_xor(v, 8,64);                     \
                     v += __shfl_xor(v,16,64);                     \
                     v += __shfl_xor(v,32,64); }while(0)

// h'[n] = relu(dis[n]*(m[n] + sum_nbr m[s]) + b)
// wave = 1 node; 8 subgroups x 8 lanes; subgroup gathers one 128B fp16 row
// (16B/lane) => 16 edges in ONE latency round for ~90% of nodes.  Persistent
// grid-stride waves prefetch the NEXT node's row_ptr during the gather.
__global__ __launch_bounds__(256) void k_agg64(
    const h8v* __restrict__ m, const float* __restrict__ dis,
    const float* __restrict__ b,
    const int* __restrict__ row_ptr, const int* __restrict__ csr,
    float* __restrict__ h, int N, int nwaves){
  int lane = threadIdx.x & 63;
  int sub = lane >> 3, q2 = lane & 7;
  int n = (blockIdx.x*blockDim.x + threadIdx.x) >> 6;
  if (n >= N) return;
  int rp0 = row_ptr[n], rp1 = row_ptr[n+1];
  const float4* b4 = (const float4*)b;
  while (true){
    int nn = n + nwaves;
    int np0 = 0, np1 = 0;
    if (nn < N){ np0 = row_ptr[nn]; np1 = row_ptr[nn+1]; }   // prefetch (indep)
    h8v sf = m[(size_t)n*8 + q2];                            // self row (indep)
    float dn = dis[n];
    float acc0=0.f,acc1=0.f,acc2=0.f,acc3=0.f,acc4=0.f,acc5=0.f,acc6=0.f,acc7=0.f;
    int s1 = rp1;
    int j0 = rp0 + sub, j1 = rp0 + 8 + sub;
    if (j0 < s1){ h8v a = m[(size_t)csr[j0]*8 + q2]; ACC8(a); }
    if (j1 < s1){ h8v a = m[(size_t)csr[j1]*8 + q2]; ACC8(a); }
    for (int j = rp0 + 16 + sub; j < s1; j += 8){            // rare (deg>16)
      h8v a = m[(size_t)csr[j]*8 + q2]; ACC8(a);
    }
    RED3(acc0); RED3(acc1); RED3(acc2); RED3(acc3);
    RED3(acc4); RED3(acc5); RED3(acc6); RED3(acc7);
    float2 s01 = __half22float2(sf.a), s23 = __half22float2(sf.b);
    float2 s45 = __half22float2(sf.c), s67 = __half22float2(sf.d);
    float4 bb0 = b4[q2*2], bb1 = b4[q2*2+1];
    float r0 = fmaxf(fmaf(acc0 + s01.x, dn, bb0.x), 0.f);
    float r1 = fmaxf(fmaf(acc1 + s01.y, dn, bb0.y), 0.f);
    float r2 = fmaxf(fmaf(acc2 + s23.x, dn, bb0.z), 0.f);
    float r3 = fmaxf(fmaf(acc3 + s23.y, dn, bb0.w), 0.f);
    float r4 = fmaxf(fmaf(acc4 + s45.x, dn, bb1.x), 0.f);
    float r5 = fmaxf(fmaf(acc5 + s45.y, dn, bb1.y), 0.f);
    float r6 = fmaxf(fmaf(acc6 + s67.x, dn, bb1.z), 0.f);
    float r7 = fmaxf(fmaf(acc7 + s67.y, dn, bb1.w), 0.f);
    float4* hrow = (float4*)(h + (size_t)n*64);
    if (sub == 0) hrow[q2*2]   = make_float4(r0,r1,r2,r3);
    if (sub == 1) hrow[q2*2+1] = make_float4(r4,r5,r6,r7);
    if (nn >= N) break;
    n = nn; rp0 = np0; rp1 = np1;
  }
}

// layer-4 aggregation fused with output projection: per-node dot(h4, Wout)
// -> wave reduce -> atomic segment add.  No h store at all.
__global__ __launch_bounds__(256) void k_agg64_out(
    const h8v* __restrict__ m, const float* __restrict__ dis,
    const float* __restrict__ b, const float* __restrict__ Wout,
    const int* __restrict__ batch,
    const int* __restrict__ row_ptr, const int* __restrict__ csr,
    float* gsum, int N, int nwaves){
  int lane = threadIdx.x & 63;
  int sub = lane >> 3, q2 = lane & 7;
  int n = (blockIdx.x*blockDim.x + threadIdx.x) >> 6;
  if (n >= N) return;
  int rp0 = row_ptr[n], rp1 = row_ptr[n+1];
  const float4* b4 = (const float4*)b;
  const float4* wo4 = (const float4*)Wout;
  while (true){
    int nn = n + nwaves;
    int np0 = 0, np1 = 0;
    if (nn < N){ np0 = row_ptr[nn]; np1 = row_ptr[nn+1]; }   // prefetch (indep)
    h8v sf = m[(size_t)n*8 + q2];                            // self row (indep)
    float dn = dis[n];
    int bg = batch[n];
    float acc0=0.f,acc1=0.f,acc2=0.f,acc3=0.f,acc4=0.f,acc5=0.f,acc6=0.f,acc7=0.f;
    int s1 = rp1;
    int j0 = rp0 + sub, j1 = rp0 + 8 + sub;
    if (j0 < s1){ h8v a = m[(size_t)csr[j0]*8 + q2]; ACC8(a); }
    if (j1 < s1){ h8v a = m[(size_t)csr[j1]*8 + q2]; ACC8(a); }
    for (int j = rp0 + 16 + sub; j < s1; j += 8){            // rare (deg>16)
      h8v a = m[(size_t)csr[j]*8 + q2]; ACC8(a);
    }
    RED3(acc0); RED3(acc1); RED3(acc2); RED3(acc3);
    RED3(acc4); RED3(acc5); RED3(acc6); RED3(acc7);
    float2 s01 = __half22float2(sf.a), s23 = __half22float2(sf.b);
    float2 s45 = __half22float2(sf.c), s67 = __half22float2(sf.d);
    float4 bb0 = b4[q2*2], bb1 = b4[q2*2+1];
    float4 w0 = wo4[q2*2], w1 = wo4[q2*2+1];
    float r0 = fmaxf(fmaf(acc0 + s01.x, dn, bb0.x), 0.f);
    float r1 = fmaxf(fmaf(acc1 + s01.y, dn, bb0.y), 0.f);
    float r2 = fmaxf(fmaf(acc2 + s23.x, dn, bb0.z), 0.f);
    float r3 = fmaxf(fmaf(acc3 + s23.y, dn, bb0.w), 0.f);
    float r4 = fmaxf(fmaf(acc4 + s45.x, dn, bb1.x), 0.f);
    float r5 = fmaxf(fmaf(acc5 + s45.y, dn, bb1.y), 0.f);
    float r6 = fmaxf(fmaf(acc6 + s67.x, dn, bb1.z), 0.f);
    float r7 = fmaxf(fmaf(acc7 + s67.y, dn, bb1.w), 0.f);
    float p = r0*w0.x + r1*w0.y + r2*w0.z + r3*w0.w
            + r4*w1.x + r5*w1.y + r6*w1.z + r7*w1.w;
    p += __shfl_xor(p,1,64); p += __shfl_xor(p,2,64); p += __shfl_xor(p,4,64);
    if (lane == 0) atomicAdd(&gsum[bg], p);
    if (nn >= N) break;
    n = nn; rp0 = np0; rp1 = np1;
  }
}

__global__ void k_final(const float* __restrict__ gsum, const int* __restrict__ gcount,
                        const float* __restrict__ bout, float* __restrict__ out, int G){
  int g = blockIdx.x*blockDim.x + threadIdx.x;
  if (g < G){
    int c = gcount[g];
    out[g] = gsum[g]/(float)(c > 0 ? c : 1) + bout[0];
  }
}

extern "C" void kernel_launch(void* const* d_in, const int* in_sizes, int n_in,
                              void* d_out, int out_size, void* d_ws, size_t ws_size,
                              hipStream_t stream){
  const float* x    = (const float*)d_in[0];
  const int*   ei   = (const int*)d_in[1];
  const int*   batch= (const int*)d_in[2];
  const float* W1 = (const float*)d_in[3];  const float* b1 = (const float*)d_in[4];
  const float* W2 = (const float*)d_in[5];  const float* b2 = (const float*)d_in[6];
  const float* W3 = (const float*)d_in[7];  const float* b3 = (const float*)d_in[8];
  const float* W4 = (const float*)d_in[9];  const float* b4 = (const float*)d_in[10];
  const float* Wout = (const float*)d_in[11]; const float* bout = (const float*)d_in[12];
  float* out = (float*)d_out;

  const int N = in_sizes[0]/9;
  const int E = in_sizes[1]/2;
  const int G = out_size;
  const int* src = ei;        // edge_index[0]
  const int* dst = ei + E;    // edge_index[1]

  char* ws = (char*)d_ws;
  size_t off = 0;
  auto alloc = [&](size_t bytes){ void* p = ws + off; off = align256(off + bytes); return p; };
  int*   deg      = (int*)  alloc((size_t)N*4);
  int*   row_ptr  = (int*)  alloc((size_t)(N+1)*4);
  int*   csr      = (int*)  alloc((size_t)E*4);
  float* dis      = (float*)alloc((size_t)N*4);
  const int NB  = (N + 255)/256;        // 391 (< 512 required by k_scanB)
  const int NBK = (N + 127)/128;        // 782 buckets of 128 dst nodes
  const int NC  = (E + CHUNK-1)/CHUNK;  // 489 sort chunks
  int*   blockSums= (int*)  alloc((size_t)NB*4);
  int*   blockOffs= (int*)  alloc((size_t)NB*4);
  int*   hoffC    = (int*)  alloc((size_t)NC*783*4);   // per-chunk bucket offsets
  float* gsum     = (float*)alloc((size_t)G*4);
  int*   gcount   = (int*)  alloc((size_t)G*4);
  float* bufA     = (float*)alloc((size_t)N*64*4);
  h4v*   mbuf     = (h4v*)  alloc((size_t)N*64*2);   // fp16 message rows (128B)
  float* xagg     = (float*)mbuf;  // layer-1 9-feat aggregate (N*9*4 <= N*128)
  float* xs       = bufA;   // premultiplied x aliases bufA (freed by k_lin1 write)
  int*   binned   = (int*)bufA;  // E*4 = 4MB <= N*64*4; consumed by k_gather
                                 // BEFORE k_premul writes xs into the same region

  const int EN = (E > N) ? E : N;
  const int AGG_BLOCKS = 2048;             // persistent: 8 blocks/CU on 256 CUs
  const int AGG_WAVES  = AGG_BLOCKS*4;     // 4 waves/block, 1 node each per step

  k_zero     <<<(N+255)/256, 256, 0, stream>>>(deg, gsum, gcount, N, G);
  k_deg      <<<(EN+255)/256, 256, 0, stream>>>(dst, batch, deg, gcount, E, N);
  k_scanA    <<<NB, 256, 0, stream>>>(deg, blockSums, N);
  k_scanB    <<<1, 512, 0, stream>>>(blockSums, blockOffs, NB);
  k_scanC    <<<NB, 256, 0, stream>>>(deg, blockOffs, row_ptr, dis, N);
  k_sortchunk<<<NC, 256, 0, stream>>>(src, dst, binned, hoffC, E);
  k_gather   <<<NBK, 256, 0, stream>>>(binned, hoffC, row_ptr, csr, N, NC);

  // layer 1: premultiply, aggregate (9 feats), then transform
  k_premul<<<(N*9+255)/256, 256, 0, stream>>>(x, dis, xs, N);
  k_agg9  <<<(N*9+255)/256, 256, 0, stream>>>(xs, dis, row_ptr, csr, xagg, N);
  k_lin1  <<<(N*64+255)/256, 256, 0, stream>>>(xagg, W1, b1, bufA, N);

  // layers 2-3: MFMA transform (dis premult, fp16 store) then aggregate
  const float* Ws[2] = {W2, W3};
  const float* bs[2] = {b2, b3};
  for (int l = 0; l < 2; l++){
    k_lin64_mfma<<<256, 256, 0, stream>>>(bufA, Ws[l], dis, (__half*)mbuf, N);
    k_agg64<<<AGG_BLOCKS, 256, 0, stream>>>((const h8v*)mbuf, dis, bs[l],
                                            row_ptr, csr, bufA, N, AGG_WAVES);
  }

  // layer 4: transform, then aggregation fused with output projection + pool
  k_lin64_mfma<<<256, 256, 0, stream>>>(bufA, W4, dis, (__half*)mbuf, N);
  k_agg64_out<<<AGG_BLOCKS, 256, 0, stream>>>((const h8v*)mbuf, dis, b4, Wout, batch,
                                              row_ptr, csr, gsum, N, AGG_WAVES);

  k_final<<<(G+255)/256, 256, 0, stream>>>(gsum, gcount, bout, out, G);
}

// Round 7
// 379.155 us; speedup vs baseline: 3.7552x; 1.1898x over previous
//
#include <hip/hip_runtime.h>
#include <hip/hip_fp16.h>

// GCN: 4x (gcn_conv + relu) + global mean pool + linear out.
// N=100000 nodes, E=1000000 edges, G=4096 graphs, F_IN=9, H=64.
// R1: wave-per-node gather MLP restructure; layer-4 agg fused with out-proj.
// R2 (FAILED, 237us): global bucket-cursor scatter -- atomic contention.
// R3: scatter-free CSR build (LDS chunk sort + single-writer bucket gather).
// R4: fp16 message rows.  FETCH halved, time flat => NOT byte-bound.
// R5: 8x8 subgroups + persistent waves + row_ptr prefetch: 72->63us/agg.
// R6 (FAILED): edge-centric LDS-atomic aggregation -- LDS atomics serialized.
// R7: standalone MFMA lin64 -- NET NEGATIVE (+13us/instance vs VALU lin64)
//     but end-to-end VALIDATED the gfx950 16x16x32_f16 fragment layouts.
// R8: delete the lin64 kernel class entirely.  The agg wave already holds the
//     node's full h in registers after the shuffle-reduce, so the next-layer
//     transform m' = (dis*h) @ W fuses into the epilogue: batch 16 nodes' rows
//     (fp16, x dis) in a per-wave 16x72-half LDS tile (pad -> 2-way banks),
//     8 MFMAs with SWAPPED operands (A = W^T frags in regs, B = h^T from LDS)
//     so D = m'[node][4 contig feats] -> vector 8B stores.  h never touches
//     memory (saves 51MB traffic/layer + 3 kernels).  Same fusion for lin1.

static inline size_t align256(size_t x){ return (x + 255) & ~size_t(255); }

#define CHUNK 2048          // edges per sort chunk

struct __align__(8)  h4v { __half2 a, b; };        // 4 halves = 8B
struct __align__(16) h8v { __half2 a, b, c, d; };  // 8 halves = 16B (agg gather)

typedef _Float16 f16x8 __attribute__((ext_vector_type(8)));
typedef float    f32x4 __attribute__((ext_vector_type(4)));

__global__ void k_zero(int* deg, float* gsum, int* gcount, int N, int G){
  int i = blockIdx.x*blockDim.x + threadIdx.x;
  if (i < N) deg[i] = 0;
  if (i < G){ gsum[i] = 0.f; gcount[i] = 0; }
}

__global__ void k_deg(const int* __restrict__ dst, const int* __restrict__ batch,
                      int* deg, int* gcount, int E, int N){
  int i = blockIdx.x*blockDim.x + threadIdx.x;
  if (i < E) atomicAdd(&deg[dst[i]], 1);
  if (i < N) atomicAdd(&gcount[batch[i]], 1);
}

__global__ void k_scanA(const int* __restrict__ deg, int* blockSums, int N){
  __shared__ int s[256];
  int t = threadIdx.x; int i = blockIdx.x*256 + t;
  s[t] = (i < N) ? deg[i] : 0;
  __syncthreads();
  for (int off=128; off>0; off>>=1){ if (t < off) s[t] += s[t+off]; __syncthreads(); }
  if (t==0) blockSums[blockIdx.x] = s[0];
}

// single-block exclusive scan of up to 512 block sums (NB=391 here)
__global__ void k_scanB(const int* __restrict__ blockSums, int* blockOffs, int NB){
  __shared__ int s[512];
  int t = threadIdx.x;
  int v = (t < NB) ? blockSums[t] : 0;
  s[t] = v; __syncthreads();
  for (int off=1; off<512; off<<=1){
    int add = (t>=off) ? s[t-off] : 0; __syncthreads();
    s[t] += add; __syncthreads();
  }
  if (t < NB) blockOffs[t] = s[t] - v;
}

// exclusive scan -> row_ptr; also dis
__global__ void k_scanC(const int* __restrict__ deg, const int* __restrict__ blockOffs,
                        int* row_ptr, float* dis, int N){
  __shared__ int s[256];
  int t = threadIdx.x; int i = blockIdx.x*256 + t;
  int v = (i < N) ? deg[i] : 0;
  s[t] = v; __syncthreads();
  for (int off=1; off<256; off<<=1){
    int add = (t>=off) ? s[t-off] : 0; __syncthreads();
    s[t] += add; __syncthreads();
  }
  if (i < N){
    int row = blockOffs[blockIdx.x] + s[t] - v;   // exclusive
    row_ptr[i] = row;
    dis[i] = rsqrtf((float)(v + 1));              // +1 self-loop; deg>=1
    if (i == N-1) row_ptr[N] = blockOffs[blockIdx.x] + s[t];
  }
}

// pass 1: sort a 2048-edge chunk by bucket entirely in LDS, emit the sorted
// image (coalesced) + the chunk's 783-entry bucket-offset row (coalesced).
// Entry packed as (src<<7)|(dst&127); src < 2^17 fits.
__global__ __launch_bounds__(256) void k_sortchunk(
    const int* __restrict__ src, const int* __restrict__ dst,
    int* __restrict__ binned, int* __restrict__ hoffC, int E){
  __shared__ int hcnt[1024];            // 782 used; padded pow2 for scan
  __shared__ int simg[CHUNK];
  int c = blockIdx.x, t = threadIdx.x;
  int e0 = c*CHUNK;
  int cnt = E - e0; if (cnt > CHUNK) cnt = CHUNK;

  for (int i = t; i < 1024; i += 256) hcnt[i] = 0;
  __syncthreads();

  int b_[8], r_[8], v_[8];              // static-indexed (stays in VGPRs)
  #pragma unroll
  for (int j = 0; j < 8; j++){
    int i = t + j*256;
    if (i < cnt){
      int d = dst[e0+i];
      int s = src[e0+i];
      int b = d >> 7;
      b_[j] = b;
      r_[j] = atomicAdd(&hcnt[b], 1);
      v_[j] = (s << 7) | (d & 127);
    } else b_[j] = -1;
  }
  __syncthreads();

  // in-place Hillis-Steele inclusive scan of hcnt[0..1023]
  int own[4];
  #pragma unroll
  for (int j = 0; j < 4; j++) own[j] = hcnt[t + j*256];
  for (int off = 1; off < 1024; off <<= 1){
    int nv[4];
    #pragma unroll
    for (int j = 0; j < 4; j++){
      int i = t + j*256;
      nv[j] = hcnt[i] + ((i >= off) ? hcnt[i-off] : 0);
    }
    __syncthreads();
    #pragma unroll
    for (int j = 0; j < 4; j++) hcnt[t + j*256] = nv[j];
    __syncthreads();
  }
  // inclusive -> exclusive
  #pragma unroll
  for (int j = 0; j < 4; j++) hcnt[t + j*256] -= own[j];
  __syncthreads();

  // emit bucket-offset row (hcnt[782] == cnt since buckets >=782 are empty)
  for (int i = t; i < 783; i += 256) hoffC[c*783 + i] = hcnt[i];

  // place edges bucket-major in LDS
  #pragma unroll
  for (int j = 0; j < 8; j++)
    if (b_[j] >= 0) simg[hcnt[b_[j]] + r_[j]] = v_[j];
  __syncthreads();

  // coalesced stream-out of the sorted chunk image
  for (int i = t; i < cnt; i += 256) binned[e0 + i] = simg[i];
}

// pass 2: WG per bucket gathers its segments from every chunk image and writes
// its own csr region (single-writer, full-line writebacks).  Per-node order
// resolved with LDS cursors.
__global__ __launch_bounds__(256) void k_gather(
    const int* __restrict__ binned, const int* __restrict__ hoffC,
    const int* __restrict__ row_ptr,
    int* __restrict__ csr, int N, int NC){
  __shared__ int lcur[128];
  int b = blockIdx.x, t = threadIdx.x;
  int n0 = b << 7;
  int nn = N - n0; if (nn > 128) nn = 128;
  if (t < nn) lcur[t] = row_ptr[n0 + t];
  __syncthreads();
  for (int c = t; c < NC; c += 256){
    int o0 = hoffC[c*783 + b];
    int o1 = hoffC[c*783 + b + 1];
    int base = c*CHUNK;
    for (int k = o0; k < o1; k++){
      int v = binned[base + k];
      int pos = atomicAdd(&lcur[v & 127], 1);
      csr[pos] = v >> 7;
    }
  }
}

// xs[n] = x[n] * dis[n]  (premultiply so the gather loop has one load per edge)
__global__ void k_premul(const float* __restrict__ x, const float* __restrict__ dis,
                         float* __restrict__ xs, int N){
  int i = blockIdx.x*blockDim.x + threadIdx.x;
  if (i < N*9) xs[i] = x[i]*dis[i/9];
}

// layer-1 aggregation over xs (9 features): thread per (node, feature), unroll-4 MLP
__global__ void k_agg9(const float* __restrict__ xs, const float* __restrict__ dis,
                       const int* __restrict__ row_ptr, const int* __restrict__ csr,
                       float* __restrict__ xagg, int N){
  int tid = blockIdx.x*blockDim.x + threadIdx.x;
  if (tid >= N*9) return;
  int n = tid/9, f = tid - n*9;
  float dn = dis[n];
  int s0 = row_ptr[n], s1 = row_ptr[n+1];
  float a0 = xs[tid];                 // self-loop term (x[n]*dis[n])
  float a1 = 0.f, a2 = 0.f, a3 = 0.f;
  int j = s0;
  for (; j + 3 < s1; j += 4){
    int e0 = csr[j], e1 = csr[j+1], e2 = csr[j+2], e3 = csr[j+3];
    a0 += xs[e0*9+f];
    a1 += xs[e1*9+f];
    a2 += xs[e2*9+f];
    a3 += xs[e3*9+f];
  }
  for (; j < s1; j++) a0 += xs[csr[j]*9+f];
  xagg[tid] = ((a0+a1)+(a2+a3))*dn;
}

// MFMA epilogue shared by the fused kernels.  hlw = this wave's 16x72-half
// LDS tile (row i = node wid + i*nwaves, cols 0..63 = dis*h fp16, 64..71 pad).
// Computes m' = (dis*h) @ Wn via D = A.B with A = Wn^T frags, B = h^T:
//   A[i][k]: lane(lm,lk) reg j -> Wn[(kb*32+lk*8+j)*64 + ft*16 + lm]
//   B[k][c]: lane(lm,lk) reg j -> hl[c=lm][kb*32+lk*8+j]  (ds_read_b128)
//   D[i][c]: lane(lm,lk) reg j -> m'[node lm][ft*16 + lk*4 + j]  (8B store)
__device__ __forceinline__ void mfma_epilogue(
    const _Float16* hlw, const f16x8 (&wf)[4][2],
    __half* __restrict__ mo, int wid, int nwaves, int N, int lane){
  int lm = lane & 15, lk = lane >> 4;
  f16x8 hb0 = *(const f16x8*)(hlw + lm*72 + lk*8);
  f16x8 hb1 = *(const f16x8*)(hlw + lm*72 + 32 + lk*8);
  int node = wid + lm*nwaves;
  bool ok = (node < N);
  __half* row = mo + (size_t)node*64;
  #pragma unroll
  for (int ft = 0; ft < 4; ft++){
    f32x4 a = {0.f, 0.f, 0.f, 0.f};
    a = __builtin_amdgcn_mfma_f32_16x16x32_f16(wf[ft][0], hb0, a, 0, 0, 0);
    a = __builtin_amdgcn_mfma_f32_16x16x32_f16(wf[ft][1], hb1, a, 0, 0, 0);
    if (ok){
      h4v o;
      o.a = __floats2half2_rn(a[0], a[1]);
      o.b = __floats2half2_rn(a[2], a[3]);
      *(h4v*)(row + ft*16 + lk*4) = o;
    }
  }
}

#define LOAD_WFRAGS(Wn)                                                    \
  f16x8 wf[4][2];                                                          \
  { int lm_ = lane & 15, lk_ = lane >> 4;                                  \
    _Pragma("unroll") for (int ft = 0; ft < 4; ft++)                       \
    _Pragma("unroll") for (int kb = 0; kb < 2; kb++)                       \
    _Pragma("unroll") for (int j = 0; j < 8; j++)                          \
      wf[ft][kb][j] = (_Float16)Wn[(kb*32 + lk_*8 + j)*64 + ft*16 + lm_]; }

// layer 1 transform fused with next-layer message build:
// h1 = relu(xagg@W1+b1); m2 = fp16((dis*h1) @ W2).  h1 never stored.
__global__ __launch_bounds__(256) void k_lin1_fused(
    const float* __restrict__ xagg, const float* __restrict__ W1,
    const float* __restrict__ b1, const float* __restrict__ dis,
    const float* __restrict__ W2, __half* __restrict__ mo, int N, int nwaves){
  __shared__ float W1l[576];
  __shared__ float b1l[64];
  __shared__ _Float16 hl[4][16*72];
  int t = threadIdx.x;
  for (int i = t; i < 576; i += 256) W1l[i] = W1[i];
  if (t < 64) b1l[t] = b1[t];
  __syncthreads();
  int lane = t & 63, w = t >> 6;
  int wid = (blockIdx.x*blockDim.x + t) >> 6;
  LOAD_WFRAGS(W2)
  _Float16* hlw = hl[w];
  for (int i = 0; i < 16; i++){
    int n = wid + i*nwaves;
    _Float16 hv = (_Float16)0.f;
    if (n < N){
      float acc = b1l[lane];
      #pragma unroll
      for (int k = 0; k < 9; k++) acc = fmaf(xagg[n*9+k], W1l[k*64+lane], acc);
      hv = (_Float16)(fmaxf(acc, 0.f) * dis[n]);
    }
    hlw[i*72 + lane] = hv;
  }
  mfma_epilogue(hlw, wf, mo, wid, nwaves, N, lane);
}

#define ACC8(a)  do{ float2 t_;                                    \
  t_ = __half22float2((a).a); acc0 += t_.x; acc1 += t_.y;          \
  t_ = __half22float2((a).b); acc2 += t_.x; acc3 += t_.y;          \
  t_ = __half22float2((a).c); acc4 += t_.x; acc5 += t_.y;          \
  t_ = __half22float2((a).d); acc6 += t_.x; acc7 += t_.y; }while(0)

#define RED3(v)  do{ v += __shfl_xor(v, 8,64);                     \
                     v += __shfl_xor(v,16,64);                     \
                     v += __shfl_xor(v,32,64); }while(0)

// layers 2,3: R5 gather (8x8 subgroups, prefetch) + fused next-layer transform.
// h = relu(dn*(sum m + self) + b) stays in registers -> fp16(dn*h) into the
// wave's LDS tile -> MFMA epilogue writes m_next.  h never touches memory.
__global__ __launch_bounds__(256) void k_agg_fused(
    const h8v* __restrict__ m, const float* __restrict__ dis,
    const float* __restrict__ b, const float* __restrict__ Wn,
    const int* __restrict__ row_ptr, const int* __restrict__ csr,
    __half* __restrict__ mo, int N, int nwaves){
  __shared__ _Float16 hl[4][16*72];
  int t = threadIdx.x;
  int lane = t & 63, w = t >> 6;
  int sub = lane >> 3, q2 = lane & 7;
  int wid = (blockIdx.x*blockDim.x + t) >> 6;
  LOAD_WFRAGS(Wn)
  _Float16* hlw = hl[w];
  const float4* b4 = (const float4*)b;
  int n = wid;
  int rp0 = 0, rp1 = 0;
  if (n < N){ rp0 = row_ptr[n]; rp1 = row_ptr[n+1]; }
  for (int i = 0; i < 16; i++){
    int nn = wid + (i+1)*nwaves;
    int np0 = 0, np1 = 0;
    if (i < 15 && nn < N){ np0 = row_ptr[nn]; np1 = row_ptr[nn+1]; }  // prefetch
    if (n < N){
      h8v sf = m[(size_t)n*8 + q2];
      float dn = dis[n];
      float acc0=0.f,acc1=0.f,acc2=0.f,acc3=0.f,acc4=0.f,acc5=0.f,acc6=0.f,acc7=0.f;
      int s1 = rp1;
      int j0 = rp0 + sub, j1 = rp0 + 8 + sub;
      if (j0 < s1){ h8v a = m[(size_t)csr[j0]*8 + q2]; ACC8(a); }
      if (j1 < s1){ h8v a = m[(size_t)csr[j1]*8 + q2]; ACC8(a); }
      for (int j = rp0 + 16 + sub; j < s1; j += 8){            // rare (deg>16)
        h8v a = m[(size_t)csr[j]*8 + q2]; ACC8(a);
      }
      RED3(acc0); RED3(acc1); RED3(acc2); RED3(acc3);
      RED3(acc4); RED3(acc5); RED3(acc6); RED3(acc7);
      float2 s01 = __half22float2(sf.a), s23 = __half22float2(sf.b);
      float2 s45 = __half22float2(sf.c), s67 = __half22float2(sf.d);
      float4 bb0 = b4[q2*2], bb1 = b4[q2*2+1];
      float r0 = fmaxf(fmaf(acc0 + s01.x, dn, bb0.x), 0.f);
      float r1 = fmaxf(fmaf(acc1 + s01.y, dn, bb0.y), 0.f);
      float r2 = fmaxf(fmaf(acc2 + s23.x, dn, bb0.z), 0.f);
      float r3 = fmaxf(fmaf(acc3 + s23.y, dn, bb0.w), 0.f);
      float r4 = fmaxf(fmaf(acc4 + s45.x, dn, bb1.x), 0.f);
      float r5 = fmaxf(fmaf(acc5 + s45.y, dn, bb1.y), 0.f);
      float r6 = fmaxf(fmaf(acc6 + s67.x, dn, bb1.z), 0.f);
      float r7 = fmaxf(fmaf(acc7 + s67.y, dn, bb1.w), 0.f);
      if (sub == 0){
        h8v hv;
        hv.a = __floats2half2_rn(r0*dn, r1*dn);
        hv.b = __floats2half2_rn(r2*dn, r3*dn);
        hv.c = __floats2half2_rn(r4*dn, r5*dn);
        hv.d = __floats2half2_rn(r6*dn, r7*dn);
        *(h8v*)(hlw + i*72 + q2*8) = hv;
      }
    } else {
      if (sub == 0){
        h8v z;
        z.a = __floats2half2_rn(0.f, 0.f); z.b = z.a; z.c = z.a; z.d = z.a;
        *(h8v*)(hlw + i*72 + q2*8) = z;
      }
    }
    n = nn; rp0 = np0; rp1 = np1;
  }
  mfma_epilogue(hlw, wf, mo, wid, nwaves, N, lane);
}

// layer-4 aggregation fused with output projection: per-node dot(h4, Wout)
// -> wave reduce -> atomic segment add.  No h store at all.
__global__ __launch_bounds__(256) void k_agg64_out(
    const h8v* __restrict__ m, const float* __restrict__ dis,
    const float* __restrict__ b, const float* __restrict__ Wout,
    const int* __restrict__ batch,
    const int* __restrict__ row_ptr, const int* __restrict__ csr,
    float* gsum, int N, int nwaves){
  int lane = threadIdx.x & 63;
  int sub = lane >> 3, q2 = lane & 7;
  int n = (blockIdx.x*blockDim.x + threadIdx.x) >> 6;
  if (n >= N) return;
  int rp0 = row_ptr[n], rp1 = row_ptr[n+1];
  const float4* b4 = (const float4*)b;
  const float4* wo4 = (const float4*)Wout;
  while (true){
    int nn = n + nwaves;
    int np0 = 0, np1 = 0;
    if (nn < N){ np0 = row_ptr[nn]; np1 = row_ptr[nn+1]; }   // prefetch (indep)
    h8v sf = m[(size_t)n*8 + q2];                            // self row (indep)
    float dn = dis[n];
    int bg = batch[n];
    float acc0=0.f,acc1=0.f,acc2=0.f,acc3=0.f,acc4=0.f,acc5=0.f,acc6=0.f,acc7=0.f;
    int s1 = rp1;
    int j0 = rp0 + sub, j1 = rp0 + 8 + sub;
    if (j0 < s1){ h8v a = m[(size_t)csr[j0]*8 + q2]; ACC8(a); }
    if (j1 < s1){ h8v a = m[(size_t)csr[j1]*8 + q2]; ACC8(a); }
    for (int j = rp0 + 16 + sub; j < s1; j += 8){            // rare (deg>16)
      h8v a = m[(size_t)csr[j]*8 + q2]; ACC8(a);
    }
    RED3(acc0); RED3(acc1); RED3(acc2); RED3(acc3);
    RED3(acc4); RED3(acc5); RED3(acc6); RED3(acc7);
    float2 s01 = __half22float2(sf.a), s23 = __half22float2(sf.b);
    float2 s45 = __half22float2(sf.c), s67 = __half22float2(sf.d);
    float4 bb0 = b4[q2*2], bb1 = b4[q2*2+1];
    float4 w0 = wo4[q2*2], w1 = wo4[q2*2+1];
    float r0 = fmaxf(fmaf(acc0 + s01.x, dn, bb0.x), 0.f);
    float r1 = fmaxf(fmaf(acc1 + s01.y, dn, bb0.y), 0.f);
    float r2 = fmaxf(fmaf(acc2 + s23.x, dn, bb0.z), 0.f);
    float r3 = fmaxf(fmaf(acc3 + s23.y, dn, bb0.w), 0.f);
    float r4 = fmaxf(fmaf(acc4 + s45.x, dn, bb1.x), 0.f);
    float r5 = fmaxf(fmaf(acc5 + s45.y, dn, bb1.y), 0.f);
    float r6 = fmaxf(fmaf(acc6 + s67.x, dn, bb1.z), 0.f);
    float r7 = fmaxf(fmaf(acc7 + s67.y, dn, bb1.w), 0.f);
    float p = r0*w0.x + r1*w0.y + r2*w0.z + r3*w0.w
            + r4*w1.x + r5*w1.y + r6*w1.z + r7*w1.w;
    p += __shfl_xor(p,1,64); p += __shfl_xor(p,2,64); p += __shfl_xor(p,4,64);
    if (lane == 0) atomicAdd(&gsum[bg], p);
    if (nn >= N) break;
    n = nn; rp0 = np0; rp1 = np1;
  }
}

__global__ void k_final(const float* __restrict__ gsum, const int* __restrict__ gcount,
                        const float* __restrict__ bout, float* __restrict__ out, int G){
  int g = blockIdx.x*blockDim.x + threadIdx.x;
  if (g < G){
    int c = gcount[g];
    out[g] = gsum[g]/(float)(c > 0 ? c : 1) + bout[0];
  }
}

extern "C" void kernel_launch(void* const* d_in, const int* in_sizes, int n_in,
                              void* d_out, int out_size, void* d_ws, size_t ws_size,
                              hipStream_t stream){
  const float* x    = (const float*)d_in[0];
  const int*   ei   = (const int*)d_in[1];
  const int*   batch= (const int*)d_in[2];
  const float* W1 = (const float*)d_in[3];  const float* b1 = (const float*)d_in[4];
  const float* W2 = (const float*)d_in[5];  const float* b2 = (const float*)d_in[6];
  const float* W3 = (const float*)d_in[7];  const float* b3 = (const float*)d_in[8];
  const float* W4 = (const float*)d_in[9];  const float* b4 = (const float*)d_in[10];
  const float* Wout = (const float*)d_in[11]; const float* bout = (const float*)d_in[12];
  float* out = (float*)d_out;

  const int N = in_sizes[0]/9;
  const int E = in_sizes[1]/2;
  const int G = out_size;
  const int* src = ei;        // edge_index[0]
  const int* dst = ei + E;    // edge_index[1]

  char* ws = (char*)d_ws;
  size_t off = 0;
  auto alloc = [&](size_t bytes){ void* p = ws + off; off = align256(off + bytes); return p; };
  int*   deg      = (int*)  alloc((size_t)N*4);
  int*   row_ptr  = (int*)  alloc((size_t)(N+1)*4);
  int*   csr      = (int*)  alloc((size_t)E*4);
  float* dis      = (float*)alloc((size_t)N*4);
  const int NB  = (N + 255)/256;        // 391 (< 512 required by k_scanB)
  const int NBK = (N + 127)/128;        // 782 buckets of 128 dst nodes
  const int NC  = (E + CHUNK-1)/CHUNK;  // 489 sort chunks
  int*   blockSums= (int*)  alloc((size_t)NB*4);
  int*   blockOffs= (int*)  alloc((size_t)NB*4);
  int*   hoffC    = (int*)  alloc((size_t)NC*783*4);   // per-chunk bucket offsets
  float* gsum     = (float*)alloc((size_t)G*4);
  int*   gcount   = (int*)  alloc((size_t)G*4);
  __half* mA      = (__half*)alloc((size_t)N*64*2);  // fp16 message ping
  __half* mB      = (__half*)alloc((size_t)N*64*2);  // fp16 message pong
  // aliases (lifetimes verified):
  int*   binned   = (int*)mA;              // 4MB <= 12.8MB; dead after k_gather
  float* xs       = (float*)mB;            // 3.6MB; dead after k_agg9
  float* xagg     = xs + (size_t)N*9;      // 3.6MB; dead after k_lin1_fused
  // m2 = mA (written by lin1_fused, after binned dead)
  // m3 = mB (written by aggF layer2, after xs/xagg dead)
  // m4 = mA (written by aggF layer3, after m2 dead)

  const int EN = (E > N) ? E : N;
  const int AGG_BLOCKS = 2048;             // persistent: 8 blocks/CU on 256 CUs
  const int AGG_WAVES  = AGG_BLOCKS*4;     // 8192 waves; 16*8192 >= N (batch=16)

  k_zero     <<<(N+255)/256, 256, 0, stream>>>(deg, gsum, gcount, N, G);
  k_deg      <<<(EN+255)/256, 256, 0, stream>>>(dst, batch, deg, gcount, E, N);
  k_scanA    <<<NB, 256, 0, stream>>>(deg, blockSums, N);
  k_scanB    <<<1, 512, 0, stream>>>(blockSums, blockOffs, NB);
  k_scanC    <<<NB, 256, 0, stream>>>(deg, blockOffs, row_ptr, dis, N);
  k_sortchunk<<<NC, 256, 0, stream>>>(src, dst, binned, hoffC, E);
  k_gather   <<<NBK, 256, 0, stream>>>(binned, hoffC, row_ptr, csr, N, NC);

  // layer 1: premultiply, aggregate (9 feats), transform fused with m2 build
  k_premul<<<(N*9+255)/256, 256, 0, stream>>>(x, dis, xs, N);
  k_agg9  <<<(N*9+255)/256, 256, 0, stream>>>(xs, dis, row_ptr, csr, xagg, N);
  k_lin1_fused<<<AGG_BLOCKS, 256, 0, stream>>>(xagg, W1, b1, dis, W2, mA, N, AGG_WAVES);

  // layer 2: aggregate m2 -> h2 (regs) -> m3   (uses b2, W3)
  k_agg_fused<<<AGG_BLOCKS, 256, 0, stream>>>((const h8v*)mA, dis, b2, W3,
                                              row_ptr, csr, mB, N, AGG_WAVES);
  // layer 3: aggregate m3 -> h3 (regs) -> m4   (uses b3, W4)
  k_agg_fused<<<AGG_BLOCKS, 256, 0, stream>>>((const h8v*)mB, dis, b3, W4,
                                              row_ptr, csr, mA, N, AGG_WAVES);
  // layer 4: aggregate m4 -> h4 (regs) -> Wout dot -> pooled sums
  k_agg64_out<<<AGG_BLOCKS, 256, 0, stream>>>((const h8v*)mA, dis, b4, Wout, batch,
                                              row_ptr, csr, gsum, N, AGG_WAVES);

  k_final<<<(G+255)/256, 256, 0, stream>>>(gsum, gcount, bout, out, G);
}

// Round 10
// 353.793 us; speedup vs baseline: 4.0244x; 1.0717x over previous
//
#include <hip/hip_runtime.h>
#include <hip/hip_fp16.h>

// GCN: 4x (gcn_conv + relu) + global mean pool + linear out.
// N=100000 nodes, E=1000000 edges, G=4096 graphs, F_IN=9, H=64.
// R1: wave-per-node gather MLP restructure; layer-4 agg fused with out-proj.
// R2 (FAILED, 237us): global bucket-cursor scatter -- atomic contention.
// R3: scatter-free CSR build (LDS chunk sort + single-writer bucket gather).
// R4: fp16 message rows.  FETCH halved, time flat => NOT byte-bound.
// R5: 8x8 subgroups + persistent waves + row_ptr prefetch: 72->63us/agg.
// R6 (FAILED): edge-centric LDS-atomic aggregation -- LDS atomics serialized.
// R7: standalone MFMA lin64 net-negative, but VALIDATED 16x16x32_f16 layouts.
// R8: lin64 deleted; transform fused into agg epilogue via MFMA.  451 -> 379us.
// R9: 2-deep software pipeline across nodes (named A/B register sets).
// R10 (COMPILE FAIL): ACC8's macro parameter was named `a` while the body
//     reads member `.a` -- the preprocessor substitutes member-name tokens
//     too, so ACC8(g0_) -> (g0_).g0_.  R5-R8 worked only because every call
//     site used a variable literally named `a`.  LESSON: macro params must
//     not collide with member names.  R11 = R9 with the param renamed `g_`.

static inline size_t align256(size_t x){ return (x + 255) & ~size_t(255); }

#define CHUNK 2048          // edges per sort chunk

struct __align__(8)  h4v { __half2 a, b; };        // 4 halves = 8B
struct __align__(16) h8v { __half2 a, b, c, d; };  // 8 halves = 16B (agg gather)

typedef _Float16 f16x8 __attribute__((ext_vector_type(8)));
typedef float    f32x4 __attribute__((ext_vector_type(4)));

__global__ void k_zero(int* deg, float* gsum, int* gcount, int N, int G){
  int i = blockIdx.x*blockDim.x + threadIdx.x;
  if (i < N) deg[i] = 0;
  if (i < G){ gsum[i] = 0.f; gcount[i] = 0; }
}

__global__ void k_deg(const int* __restrict__ dst, const int* __restrict__ batch,
                      int* deg, int* gcount, int E, int N){
  int i = blockIdx.x*blockDim.x + threadIdx.x;
  if (i < E) atomicAdd(&deg[dst[i]], 1);
  if (i < N) atomicAdd(&gcount[batch[i]], 1);
}

__global__ void k_scanA(const int* __restrict__ deg, int* blockSums, int N){
  __shared__ int s[256];
  int t = threadIdx.x; int i = blockIdx.x*256 + t;
  s[t] = (i < N) ? deg[i] : 0;
  __syncthreads();
  for (int off=128; off>0; off>>=1){ if (t < off) s[t] += s[t+off]; __syncthreads(); }
  if (t==0) blockSums[blockIdx.x] = s[0];
}

// single-block exclusive scan of up to 512 block sums (NB=391 here)
__global__ void k_scanB(const int* __restrict__ blockSums, int* blockOffs, int NB){
  __shared__ int s[512];
  int t = threadIdx.x;
  int v = (t < NB) ? blockSums[t] : 0;
  s[t] = v; __syncthreads();
  for (int off=1; off<512; off<<=1){
    int add = (t>=off) ? s[t-off] : 0; __syncthreads();
    s[t] += add; __syncthreads();
  }
  if (t < NB) blockOffs[t] = s[t] - v;
}

// exclusive scan -> row_ptr; also dis
__global__ void k_scanC(const int* __restrict__ deg, const int* __restrict__ blockOffs,
                        int* row_ptr, float* dis, int N){
  __shared__ int s[256];
  int t = threadIdx.x; int i = blockIdx.x*256 + t;
  int v = (i < N) ? deg[i] : 0;
  s[t] = v; __syncthreads();
  for (int off=1; off<256; off<<=1){
    int add = (t>=off) ? s[t-off] : 0; __syncthreads();
    s[t] += add; __syncthreads();
  }
  if (i < N){
    int row = blockOffs[blockIdx.x] + s[t] - v;   // exclusive
    row_ptr[i] = row;
    dis[i] = rsqrtf((float)(v + 1));              // +1 self-loop; deg>=1
    if (i == N-1) row_ptr[N] = blockOffs[blockIdx.x] + s[t];
  }
}

// pass 1: sort a 2048-edge chunk by bucket entirely in LDS, emit the sorted
// image (coalesced) + the chunk's 783-entry bucket-offset row (coalesced).
// Entry packed as (src<<7)|(dst&127); src < 2^17 fits.
__global__ __launch_bounds__(256) void k_sortchunk(
    const int* __restrict__ src, const int* __restrict__ dst,
    int* __restrict__ binned, int* __restrict__ hoffC, int E){
  __shared__ int hcnt[1024];            // 782 used; padded pow2 for scan
  __shared__ int simg[CHUNK];
  int c = blockIdx.x, t = threadIdx.x;
  int e0 = c*CHUNK;
  int cnt = E - e0; if (cnt > CHUNK) cnt = CHUNK;

  for (int i = t; i < 1024; i += 256) hcnt[i] = 0;
  __syncthreads();

  int b_[8], r_[8], v_[8];              // static-indexed (stays in VGPRs)
  #pragma unroll
  for (int j = 0; j < 8; j++){
    int i = t + j*256;
    if (i < cnt){
      int d = dst[e0+i];
      int s = src[e0+i];
      int b = d >> 7;
      b_[j] = b;
      r_[j] = atomicAdd(&hcnt[b], 1);
      v_[j] = (s << 7) | (d & 127);
    } else b_[j] = -1;
  }
  __syncthreads();

  // in-place Hillis-Steele inclusive scan of hcnt[0..1023]
  int own[4];
  #pragma unroll
  for (int j = 0; j < 4; j++) own[j] = hcnt[t + j*256];
  for (int off = 1; off < 1024; off <<= 1){
    int nv[4];
    #pragma unroll
    for (int j = 0; j < 4; j++){
      int i = t + j*256;
      nv[j] = hcnt[i] + ((i >= off) ? hcnt[i-off] : 0);
    }
    __syncthreads();
    #pragma unroll
    for (int j = 0; j < 4; j++) hcnt[t + j*256] = nv[j];
    __syncthreads();
  }
  // inclusive -> exclusive
  #pragma unroll
  for (int j = 0; j < 4; j++) hcnt[t + j*256] -= own[j];
  __syncthreads();

  // emit bucket-offset row (hcnt[782] == cnt since buckets >=782 are empty)
  for (int i = t; i < 783; i += 256) hoffC[c*783 + i] = hcnt[i];

  // place edges bucket-major in LDS
  #pragma unroll
  for (int j = 0; j < 8; j++)
    if (b_[j] >= 0) simg[hcnt[b_[j]] + r_[j]] = v_[j];
  __syncthreads();

  // coalesced stream-out of the sorted chunk image
  for (int i = t; i < cnt; i += 256) binned[e0 + i] = simg[i];
}

// pass 2: WG per bucket gathers its segments from every chunk image and writes
// its own csr region (single-writer, full-line writebacks).  Per-node order
// resolved with LDS cursors.
__global__ __launch_bounds__(256) void k_gather(
    const int* __restrict__ binned, const int* __restrict__ hoffC,
    const int* __restrict__ row_ptr,
    int* __restrict__ csr, int N, int NC){
  __shared__ int lcur[128];
  int b = blockIdx.x, t = threadIdx.x;
  int n0 = b << 7;
  int nn = N - n0; if (nn > 128) nn = 128;
  if (t < nn) lcur[t] = row_ptr[n0 + t];
  __syncthreads();
  for (int c = t; c < NC; c += 256){
    int o0 = hoffC[c*783 + b];
    int o1 = hoffC[c*783 + b + 1];
    int base = c*CHUNK;
    for (int k = o0; k < o1; k++){
      int v = binned[base + k];
      int pos = atomicAdd(&lcur[v & 127], 1);
      csr[pos] = v >> 7;
    }
  }
}

// xs[n] = x[n] * dis[n]  (premultiply so the gather loop has one load per edge)
__global__ void k_premul(const float* __restrict__ x, const float* __restrict__ dis,
                         float* __restrict__ xs, int N){
  int i = blockIdx.x*blockDim.x + threadIdx.x;
  if (i < N*9) xs[i] = x[i]*dis[i/9];
}

// layer-1 aggregation over xs (9 features): thread per (node, feature), unroll-4 MLP
__global__ void k_agg9(const float* __restrict__ xs, const float* __restrict__ dis,
                       const int* __restrict__ row_ptr, const int* __restrict__ csr,
                       float* __restrict__ xagg, int N){
  int tid = blockIdx.x*blockDim.x + threadIdx.x;
  if (tid >= N*9) return;
  int n = tid/9, f = tid - n*9;
  float dn = dis[n];
  int s0 = row_ptr[n], s1 = row_ptr[n+1];
  float a0 = xs[tid];                 // self-loop term (x[n]*dis[n])
  float a1 = 0.f, a2 = 0.f, a3 = 0.f;
  int j = s0;
  for (; j + 3 < s1; j += 4){
    int e0 = csr[j], e1 = csr[j+1], e2 = csr[j+2], e3 = csr[j+3];
    a0 += xs[e0*9+f];
    a1 += xs[e1*9+f];
    a2 += xs[e2*9+f];
    a3 += xs[e3*9+f];
  }
  for (; j < s1; j++) a0 += xs[csr[j]*9+f];
  xagg[tid] = ((a0+a1)+(a2+a3))*dn;
}

// MFMA epilogue shared by the fused kernels.  hlw = this wave's 16x72-half
// LDS tile (row i = node wid + i*nwaves, cols 0..63 = dis*h fp16, 64..71 pad).
// Computes m' = (dis*h) @ Wn via D = A.B with A = Wn^T frags, B = h^T:
//   A[i][k]: lane(lm,lk) reg j -> Wn[(kb*32+lk*8+j)*64 + ft*16 + lm]
//   B[k][c]: lane(lm,lk) reg j -> hl[c=lm][kb*32+lk*8+j]  (ds_read_b128)
//   D[i][c]: lane(lm,lk) reg j -> m'[node lm][ft*16 + lk*4 + j]  (8B store)
__device__ __forceinline__ void mfma_epilogue(
    const _Float16* hlw, const f16x8 (&wf)[4][2],
    __half* __restrict__ mo, int wid, int nwaves, int N, int lane){
  int lm = lane & 15, lk = lane >> 4;
  f16x8 hb0 = *(const f16x8*)(hlw + lm*72 + lk*8);
  f16x8 hb1 = *(const f16x8*)(hlw + lm*72 + 32 + lk*8);
  int node = wid + lm*nwaves;
  bool ok = (node < N);
  __half* row = mo + (size_t)node*64;
  #pragma unroll
  for (int ft = 0; ft < 4; ft++){
    f32x4 acc = {0.f, 0.f, 0.f, 0.f};
    acc = __builtin_amdgcn_mfma_f32_16x16x32_f16(wf[ft][0], hb0, acc, 0, 0, 0);
    acc = __builtin_amdgcn_mfma_f32_16x16x32_f16(wf[ft][1], hb1, acc, 0, 0, 0);
    if (ok){
      h4v o;
      o.a = __floats2half2_rn(acc[0], acc[1]);
      o.b = __floats2half2_rn(acc[2], acc[3]);
      *(h4v*)(row + ft*16 + lk*4) = o;
    }
  }
}

#define LOAD_WFRAGS(Wn)                                                    \
  f16x8 wf[4][2];                                                          \
  { int lm_ = lane & 15, lk_ = lane >> 4;                                  \
    _Pragma("unroll") for (int ft = 0; ft < 4; ft++)                       \
    _Pragma("unroll") for (int kb = 0; kb < 2; kb++)                       \
    _Pragma("unroll") for (int j = 0; j < 8; j++)                          \
      wf[ft][kb][j] = (_Float16)Wn[(kb*32 + lk_*8 + j)*64 + ft*16 + lm_]; }

// layer 1 transform fused with next-layer message build:
// h1 = relu(xagg@W1+b1); m2 = fp16((dis*h1) @ W2).  h1 never stored.
__global__ __launch_bounds__(256) void k_lin1_fused(
    const float* __restrict__ xagg, const float* __restrict__ W1,
    const float* __restrict__ b1, const float* __restrict__ dis,
    const float* __restrict__ W2, __half* __restrict__ mo, int N, int nwaves){
  __shared__ float W1l[576];
  __shared__ float b1l[64];
  __shared__ _Float16 hl[4][16*72];
  int t = threadIdx.x;
  for (int i = t; i < 576; i += 256) W1l[i] = W1[i];
  if (t < 64) b1l[t] = b1[t];
  __syncthreads();
  int lane = t & 63, w = t >> 6;
  int wid = (blockIdx.x*blockDim.x + t) >> 6;
  LOAD_WFRAGS(W2)
  _Float16* hlw = hl[w];
  for (int i = 0; i < 16; i++){
    int n = wid + i*nwaves;
    _Float16 hv = (_Float16)0.f;
    if (n < N){
      float acc = b1l[lane];
      #pragma unroll
      for (int k = 0; k < 9; k++) acc = fmaf(xagg[n*9+k], W1l[k*64+lane], acc);
      hv = (_Float16)(fmaxf(acc, 0.f) * dis[n]);
    }
    hlw[i*72 + lane] = hv;
  }
  mfma_epilogue(hlw, wf, mo, wid, nwaves, N, lane);
}

// NOTE: param is g_ (NOT `a`): body reads members .a/.b/.c/.d and the
// preprocessor would substitute a same-named parameter into member tokens.
#define ACC8(g_)  do{ float2 t_;                                   \
  t_ = __half22float2((g_).a); acc0 += t_.x; acc1 += t_.y;         \
  t_ = __half22float2((g_).b); acc2 += t_.x; acc3 += t_.y;         \
  t_ = __half22float2((g_).c); acc4 += t_.x; acc5 += t_.y;         \
  t_ = __half22float2((g_).d); acc6 += t_.x; acc7 += t_.y; }while(0)

#define RED3(v)  do{ v += __shfl_xor(v, 8,64);                     \
                     v += __shfl_xor(v,16,64);                     \
                     v += __shfl_xor(v,32,64); }while(0)

// --- R9 pipeline stages (named register sets; no runtime-indexed arrays) ---
// ISSUE: prefetch row_ptr 2 ahead, load self row + dis, csr indices, and
// launch the node's 16 gathers.  REDUCE (next half-step) consumes them.
#define AGG_ISSUE(n_, rp0_, rp1_, rn0_, rn1_, e0_, e1_, g0_, g1_, sf_, dn_) \
  do{                                                                      \
    int nn_ = (n_) + 2*nwaves;                                             \
    rn0_ = 0; rn1_ = 0;                                                    \
    if (nn_ < N){ rn0_ = row_ptr[nn_]; rn1_ = row_ptr[nn_+1]; }            \
    e0_ = -1; e1_ = -1;                                                    \
    if ((n_) < N){                                                         \
      sf_ = m[(size_t)(n_)*8 + q2];                                        \
      dn_ = dis[n_];                                                       \
      int j0_ = (rp0_) + sub, j1_ = (rp0_) + 8 + sub;                      \
      if (j0_ < (rp1_)) e0_ = csr[j0_];                                    \
      if (j1_ < (rp1_)) e1_ = csr[j1_];                                    \
      if (e0_ >= 0) g0_ = m[(size_t)e0_*8 + q2];                           \
      if (e1_ >= 0) g1_ = m[(size_t)e1_*8 + q2];                           \
    }                                                                      \
  }while(0)

#define AGG_ACCRED(n_, rp0_, rp1_, e0_, e1_, g0_, g1_, sf_, dn_)           \
      float acc0=0.f,acc1=0.f,acc2=0.f,acc3=0.f;                           \
      float acc4=0.f,acc5=0.f,acc6=0.f,acc7=0.f;                           \
      if (e0_ >= 0) ACC8(g0_);                                             \
      if (e1_ >= 0) ACC8(g1_);                                             \
      for (int j_ = (rp0_) + 16 + sub; j_ < (rp1_); j_ += 8){              \
        h8v gx_ = m[(size_t)csr[j_]*8 + q2]; ACC8(gx_);                    \
      }                                                                    \
      RED3(acc0); RED3(acc1); RED3(acc2); RED3(acc3);                      \
      RED3(acc4); RED3(acc5); RED3(acc6); RED3(acc7);                      \
      float2 s01=__half22float2((sf_).a), s23=__half22float2((sf_).b);     \
      float2 s45=__half22float2((sf_).c), s67=__half22float2((sf_).d);     \
      float r0 = fmaxf(fmaf(acc0 + s01.x, dn_, bb0.x), 0.f);               \
      float r1 = fmaxf(fmaf(acc1 + s01.y, dn_, bb0.y), 0.f);               \
      float r2 = fmaxf(fmaf(acc2 + s23.x, dn_, bb0.z), 0.f);               \
      float r3 = fmaxf(fmaf(acc3 + s23.y, dn_, bb0.w), 0.f);               \
      float r4 = fmaxf(fmaf(acc4 + s45.x, dn_, bb1.x), 0.f);               \
      float r5 = fmaxf(fmaf(acc5 + s45.y, dn_, bb1.y), 0.f);               \
      float r6 = fmaxf(fmaf(acc6 + s67.x, dn_, bb1.z), 0.f);               \
      float r7 = fmaxf(fmaf(acc7 + s67.y, dn_, bb1.w), 0.f);

// REDUCE for the fused kernels: writes fp16(dn*h) into the wave's LDS tile
#define AGG_REDUCE(n_, rp0_, rp1_, e0_, e1_, g0_, g1_, sf_, dn_, i_)       \
  do{                                                                      \
    if ((n_) < N){                                                         \
      AGG_ACCRED(n_, rp0_, rp1_, e0_, e1_, g0_, g1_, sf_, dn_)             \
      if (sub == 0){                                                       \
        h8v hv_;                                                           \
        hv_.a = __floats2half2_rn(r0*(dn_), r1*(dn_));                     \
        hv_.b = __floats2half2_rn(r2*(dn_), r3*(dn_));                     \
        hv_.c = __floats2half2_rn(r4*(dn_), r5*(dn_));                     \
        hv_.d = __floats2half2_rn(r6*(dn_), r7*(dn_));                     \
        *(h8v*)(hlw + (i_)*72 + q2*8) = hv_;                               \
      }                                                                    \
    } else if (sub == 0){                                                  \
      h8v z_; z_.a = __floats2half2_rn(0.f, 0.f);                          \
      z_.b = z_.a; z_.c = z_.a; z_.d = z_.a;                               \
      *(h8v*)(hlw + (i_)*72 + q2*8) = z_;                                  \
    }                                                                      \
  }while(0)

// REDUCE for layer 4: Wout dot -> wave reduce -> atomic pool add
#define AGG_REDUCE_OUT(n_, rp0_, rp1_, e0_, e1_, g0_, g1_, sf_, dn_, bg_)  \
  do{                                                                      \
    if ((n_) < N){                                                         \
      AGG_ACCRED(n_, rp0_, rp1_, e0_, e1_, g0_, g1_, sf_, dn_)             \
      float p_ = r0*w0.x + r1*w0.y + r2*w0.z + r3*w0.w                     \
               + r4*w1.x + r5*w1.y + r6*w1.z + r7*w1.w;                    \
      p_ += __shfl_xor(p_,1,64); p_ += __shfl_xor(p_,2,64);                \
      p_ += __shfl_xor(p_,4,64);                                           \
      if (lane == 0) atomicAdd(&gsum[bg_], p_);                            \
    }                                                                      \
  }while(0)

// layers 2,3: pipelined gather + fused next-layer transform.
__global__ __launch_bounds__(256) void k_agg_fused(
    const h8v* __restrict__ m, const float* __restrict__ dis,
    const float* __restrict__ b, const float* __restrict__ Wn,
    const int* __restrict__ row_ptr, const int* __restrict__ csr,
    __half* __restrict__ mo, int N, int nwaves){
  __shared__ _Float16 hl[4][16*72];
  int t = threadIdx.x;
  int lane = t & 63, w = t >> 6;
  int sub = lane >> 3, q2 = lane & 7;
  int wid = (blockIdx.x*blockDim.x + t) >> 6;
  _Float16* hlw = hl[w];
  const float4* b4 = (const float4*)b;
  float4 bb0 = b4[q2*2], bb1 = b4[q2*2+1];

  int nA = wid,          rA0 = 0, rA1 = 0;
  int nB = wid + nwaves, rB0 = 0, rB1 = 0;
  if (nA < N){ rA0 = row_ptr[nA]; rA1 = row_ptr[nA+1]; }
  if (nB < N){ rB0 = row_ptr[nB]; rB1 = row_ptr[nB+1]; }
  int eA0, eA1, eB0, eB1, rnA0, rnA1, rnB0, rnB1;
  h8v gA0, gA1, sfA, gB0, gB1, sfB;
  float dnA = 0.f, dnB = 0.f;
  AGG_ISSUE(nA, rA0, rA1, rnA0, rnA1, eA0, eA1, gA0, gA1, sfA, dnA);
  for (int p = 0; p < 8; p++){
    AGG_ISSUE(nB, rB0, rB1, rnB0, rnB1, eB0, eB1, gB0, gB1, sfB, dnB);
    AGG_REDUCE(nA, rA0, rA1, eA0, eA1, gA0, gA1, sfA, dnA, 2*p);
    nA += 2*nwaves; rA0 = rnA0; rA1 = rnA1;
    if (p < 7)
      AGG_ISSUE(nA, rA0, rA1, rnA0, rnA1, eA0, eA1, gA0, gA1, sfA, dnA);
    AGG_REDUCE(nB, rB0, rB1, eB0, eB1, gB0, gB1, sfB, dnB, 2*p+1);
    nB += 2*nwaves; rB0 = rnB0; rB1 = rnB1;
  }
  LOAD_WFRAGS(Wn)            // loaded at epilogue: not live during main loop
  mfma_epilogue(hlw, wf, mo, wid, nwaves, N, lane);
}

// layer 4: pipelined gather + output projection + pool.  Fixed 16-node batch.
__global__ __launch_bounds__(256) void k_agg64_out(
    const h8v* __restrict__ m, const float* __restrict__ dis,
    const float* __restrict__ b, const float* __restrict__ Wout,
    const int* __restrict__ batch,
    const int* __restrict__ row_ptr, const int* __restrict__ csr,
    float* gsum, int N, int nwaves){
  int t = threadIdx.x;
  int lane = t & 63;
  int sub = lane >> 3, q2 = lane & 7;
  int wid = (blockIdx.x*blockDim.x + t) >> 6;
  const float4* b4 = (const float4*)b;
  const float4* wo4 = (const float4*)Wout;
  float4 bb0 = b4[q2*2], bb1 = b4[q2*2+1];
  float4 w0 = wo4[q2*2], w1 = wo4[q2*2+1];

  int nA = wid,          rA0 = 0, rA1 = 0;
  int nB = wid + nwaves, rB0 = 0, rB1 = 0;
  if (nA < N){ rA0 = row_ptr[nA]; rA1 = row_ptr[nA+1]; }
  if (nB < N){ rB0 = row_ptr[nB]; rB1 = row_ptr[nB+1]; }
  int eA0, eA1, eB0, eB1, rnA0, rnA1, rnB0, rnB1;
  h8v gA0, gA1, sfA, gB0, gB1, sfB;
  float dnA = 0.f, dnB = 0.f;
  int bgA = 0, bgB = 0;
  AGG_ISSUE(nA, rA0, rA1, rnA0, rnA1, eA0, eA1, gA0, gA1, sfA, dnA);
  if (nA < N) bgA = batch[nA];
  for (int p = 0; p < 8; p++){
    AGG_ISSUE(nB, rB0, rB1, rnB0, rnB1, eB0, eB1, gB0, gB1, sfB, dnB);
    if (nB < N) bgB = batch[nB];
    AGG_REDUCE_OUT(nA, rA0, rA1, eA0, eA1, gA0, gA1, sfA, dnA, bgA);
    nA += 2*nwaves; rA0 = rnA0; rA1 = rnA1;
    if (p < 7){
      AGG_ISSUE(nA, rA0, rA1, rnA0, rnA1, eA0, eA1, gA0, gA1, sfA, dnA);
      if (nA < N) bgA = batch[nA];
    }
    AGG_REDUCE_OUT(nB, rB0, rB1, eB0, eB1, gB0, gB1, sfB, dnB, bgB);
    nB += 2*nwaves; rB0 = rnB0; rB1 = rnB1;
  }
}

__global__ void k_final(const float* __restrict__ gsum, const int* __restrict__ gcount,
                        const float* __restrict__ bout, float* __restrict__ out, int G){
  int g = blockIdx.x*blockDim.x + threadIdx.x;
  if (g < G){
    int c = gcount[g];
    out[g] = gsum[g]/(float)(c > 0 ? c : 1) + bout[0];
  }
}

extern "C" void kernel_launch(void* const* d_in, const int* in_sizes, int n_in,
                              void* d_out, int out_size, void* d_ws, size_t ws_size,
                              hipStream_t stream){
  const float* x    = (const float*)d_in[0];
  const int*   ei   = (const int*)d_in[1];
  const int*   batch= (const int*)d_in[2];
  const float* W1 = (const float*)d_in[3];  const float* b1 = (const float*)d_in[4];
  const float* W2 = (const float*)d_in[5];  const float* b2 = (const float*)d_in[6];
  const float* W3 = (const float*)d_in[7];  const float* b3 = (const float*)d_in[8];
  const float* W4 = (const float*)d_in[9];  const float* b4 = (const float*)d_in[10];
  const float* Wout = (const float*)d_in[11]; const float* bout = (const float*)d_in[12];
  float* out = (float*)d_out;

  const int N = in_sizes[0]/9;
  const int E = in_sizes[1]/2;
  const int G = out_size;
  const int* src = ei;        // edge_index[0]
  const int* dst = ei + E;    // edge_index[1]

  char* ws = (char*)d_ws;
  size_t off = 0;
  auto alloc = [&](size_t bytes){ void* p = ws + off; off = align256(off + bytes); return p; };
  int*   deg      = (int*)  alloc((size_t)N*4);
  int*   row_ptr  = (int*)  alloc((size_t)(N+1)*4);
  int*   csr      = (int*)  alloc((size_t)E*4);
  float* dis      = (float*)alloc((size_t)N*4);
  const int NB  = (N + 255)/256;        // 391 (< 512 required by k_scanB)
  const int NBK = (N + 127)/128;        // 782 buckets of 128 dst nodes
  const int NC  = (E + CHUNK-1)/CHUNK;  // 489 sort chunks
  int*   blockSums= (int*)  alloc((size_t)NB*4);
  int*   blockOffs= (int*)  alloc((size_t)NB*4);
  int*   hoffC    = (int*)  alloc((size_t)NC*783*4);   // per-chunk bucket offsets
  float* gsum     = (float*)alloc((size_t)G*4);
  int*   gcount   = (int*)  alloc((size_t)G*4);
  __half* mA      = (__half*)alloc((size_t)N*64*2);  // fp16 message ping
  __half* mB      = (__half*)alloc((size_t)N*64*2);  // fp16 message pong
  // aliases (lifetimes verified):
  int*   binned   = (int*)mA;              // 4MB <= 12.8MB; dead after k_gather
  float* xs       = (float*)mB;            // 3.6MB; dead after k_agg9
  float* xagg     = xs + (size_t)N*9;      // 3.6MB; dead after k_lin1_fused
  // m2 = mA (written by lin1_fused, after binned dead)
  // m3 = mB (written by aggF layer2, after xs/xagg dead)
  // m4 = mA (written by aggF layer3, after m2 dead)

  const int EN = (E > N) ? E : N;
  const int AGG_BLOCKS = 2048;             // persistent: 8 blocks/CU on 256 CUs
  const int AGG_WAVES  = AGG_BLOCKS*4;     // 8192 waves; 16*8192 >= N (batch=16)

  k_zero     <<<(N+255)/256, 256, 0, stream>>>(deg, gsum, gcount, N, G);
  k_deg      <<<(EN+255)/256, 256, 0, stream>>>(dst, batch, deg, gcount, E, N);
  k_scanA    <<<NB, 256, 0, stream>>>(deg, blockSums, N);
  k_scanB    <<<1, 512, 0, stream>>>(blockSums, blockOffs, NB);
  k_scanC    <<<NB, 256, 0, stream>>>(deg, blockOffs, row_ptr, dis, N);
  k_sortchunk<<<NC, 256, 0, stream>>>(src, dst, binned, hoffC, E);
  k_gather   <<<NBK, 256, 0, stream>>>(binned, hoffC, row_ptr, csr, N, NC);

  // layer 1: premultiply, aggregate (9 feats), transform fused with m2 build
  k_premul<<<(N*9+255)/256, 256, 0, stream>>>(x, dis, xs, N);
  k_agg9  <<<(N*9+255)/256, 256, 0, stream>>>(xs, dis, row_ptr, csr, xagg, N);
  k_lin1_fused<<<AGG_BLOCKS, 256, 0, stream>>>(xagg, W1, b1, dis, W2, mA, N, AGG_WAVES);

  // layer 2: aggregate m2 -> h2 (regs) -> m3   (uses b2, W3)
  k_agg_fused<<<AGG_BLOCKS, 256, 0, stream>>>((const h8v*)mA, dis, b2, W3,
                                              row_ptr, csr, mB, N, AGG_WAVES);
  // layer 3: aggregate m3 -> h3 (regs) -> m4   (uses b3, W4)
  k_agg_fused<<<AGG_BLOCKS, 256, 0, stream>>>((const h8v*)mB, dis, b3, W4,
                                              row_ptr, csr, mA, N, AGG_WAVES);
  // layer 4: aggregate m4 -> h4 (regs) -> Wout dot -> pooled sums
  k_agg64_out<<<AGG_BLOCKS, 256, 0, stream>>>((const h8v*)mA, dis, b4, Wout, batch,
                                              row_ptr, csr, gsum, N, AGG_WAVES);

  k_final<<<(G+255)/256, 256, 0, stream>>>(gsum, gcount, bout, out, G);
}

// Round 11
// 341.350 us; speedup vs baseline: 4.1711x; 1.0365x over previous
//
#include <hip/hip_runtime.h>
#include <hip/hip_fp16.h>

// GCN: 4x (gcn_conv + relu) + global mean pool + linear out.
// N=100000 nodes, E=1000000 edges, G=4096 graphs, F_IN=9, H=64.
// R1: wave-per-node gather MLP restructure; layer-4 agg fused with out-proj.
// R2 (FAILED, 237us): global bucket-cursor scatter -- atomic contention.
// R3: scatter-free CSR build (LDS chunk sort + single-writer bucket gather).
// R4: fp16 message rows.  FETCH halved, time flat => NOT byte-bound.
// R5: 8x8 subgroups + persistent waves + row_ptr prefetch: 72->63us/agg.
// R6 (FAILED): edge-centric LDS-atomic aggregation -- LDS atomics serialized.
// R7: standalone MFMA lin64 net-negative, but VALIDATED 16x16x32_f16 layouts.
// R8: lin64 deleted; transform fused into agg epilogue via MFMA.  451 -> 379us.
// R9-R11: 2-deep A/B pipeline.  SPLIT RESULT (353.8us): agg_fused 65->~47
//     (-28%, keep) but agg64_out 60->70 (REGRESSED, occupancy 63->40%).
// R12: selective revert -- agg64_out back to R8's measured-60us while-loop;
//     agg_fused keeps the pipeline.  k_premul fused into k_scanC (dis is
//     computed there anyway; one fewer kernel + one fewer 7MB pass).

static inline size_t align256(size_t x){ return (x + 255) & ~size_t(255); }

#define CHUNK 2048          // edges per sort chunk

struct __align__(8)  h4v { __half2 a, b; };        // 4 halves = 8B
struct __align__(16) h8v { __half2 a, b, c, d; };  // 8 halves = 16B (agg gather)

typedef _Float16 f16x8 __attribute__((ext_vector_type(8)));
typedef float    f32x4 __attribute__((ext_vector_type(4)));

__global__ void k_zero(int* deg, float* gsum, int* gcount, int N, int G){
  int i = blockIdx.x*blockDim.x + threadIdx.x;
  if (i < N) deg[i] = 0;
  if (i < G){ gsum[i] = 0.f; gcount[i] = 0; }
}

__global__ void k_deg(const int* __restrict__ dst, const int* __restrict__ batch,
                      int* deg, int* gcount, int E, int N){
  int i = blockIdx.x*blockDim.x + threadIdx.x;
  if (i < E) atomicAdd(&deg[dst[i]], 1);
  if (i < N) atomicAdd(&gcount[batch[i]], 1);
}

__global__ void k_scanA(const int* __restrict__ deg, int* blockSums, int N){
  __shared__ int s[256];
  int t = threadIdx.x; int i = blockIdx.x*256 + t;
  s[t] = (i < N) ? deg[i] : 0;
  __syncthreads();
  for (int off=128; off>0; off>>=1){ if (t < off) s[t] += s[t+off]; __syncthreads(); }
  if (t==0) blockSums[blockIdx.x] = s[0];
}

// single-block exclusive scan of up to 512 block sums (NB=391 here)
__global__ void k_scanB(const int* __restrict__ blockSums, int* blockOffs, int NB){
  __shared__ int s[512];
  int t = threadIdx.x;
  int v = (t < NB) ? blockSums[t] : 0;
  s[t] = v; __syncthreads();
  for (int off=1; off<512; off<<=1){
    int add = (t>=off) ? s[t-off] : 0; __syncthreads();
    s[t] += add; __syncthreads();
  }
  if (t < NB) blockOffs[t] = s[t] - v;
}

// exclusive scan -> row_ptr, dis; fused premul: xs = x*dis (was k_premul)
__global__ void k_scanC(const int* __restrict__ deg, const int* __restrict__ blockOffs,
                        const float* __restrict__ x,
                        int* row_ptr, float* dis, float* __restrict__ xs, int N){
  __shared__ int s[256];
  int t = threadIdx.x; int i = blockIdx.x*256 + t;
  int v = (i < N) ? deg[i] : 0;
  s[t] = v; __syncthreads();
  for (int off=1; off<256; off<<=1){
    int add = (t>=off) ? s[t-off] : 0; __syncthreads();
    s[t] += add; __syncthreads();
  }
  if (i < N){
    int row = blockOffs[blockIdx.x] + s[t] - v;   // exclusive
    row_ptr[i] = row;
    float dv = rsqrtf((float)(v + 1));            // +1 self-loop; deg>=1
    dis[i] = dv;
    #pragma unroll
    for (int k = 0; k < 9; k++) xs[i*9+k] = x[i*9+k]*dv;
    if (i == N-1) row_ptr[N] = blockOffs[blockIdx.x] + s[t];
  }
}

// pass 1: sort a 2048-edge chunk by bucket entirely in LDS, emit the sorted
// image (coalesced) + the chunk's 783-entry bucket-offset row (coalesced).
// Entry packed as (src<<7)|(dst&127); src < 2^17 fits.
__global__ __launch_bounds__(256) void k_sortchunk(
    const int* __restrict__ src, const int* __restrict__ dst,
    int* __restrict__ binned, int* __restrict__ hoffC, int E){
  __shared__ int hcnt[1024];            // 782 used; padded pow2 for scan
  __shared__ int simg[CHUNK];
  int c = blockIdx.x, t = threadIdx.x;
  int e0 = c*CHUNK;
  int cnt = E - e0; if (cnt > CHUNK) cnt = CHUNK;

  for (int i = t; i < 1024; i += 256) hcnt[i] = 0;
  __syncthreads();

  int b_[8], r_[8], v_[8];              // static-indexed (stays in VGPRs)
  #pragma unroll
  for (int j = 0; j < 8; j++){
    int i = t + j*256;
    if (i < cnt){
      int d = dst[e0+i];
      int s = src[e0+i];
      int b = d >> 7;
      b_[j] = b;
      r_[j] = atomicAdd(&hcnt[b], 1);
      v_[j] = (s << 7) | (d & 127);
    } else b_[j] = -1;
  }
  __syncthreads();

  // in-place Hillis-Steele inclusive scan of hcnt[0..1023]
  int own[4];
  #pragma unroll
  for (int j = 0; j < 4; j++) own[j] = hcnt[t + j*256];
  for (int off = 1; off < 1024; off <<= 1){
    int nv[4];
    #pragma unroll
    for (int j = 0; j < 4; j++){
      int i = t + j*256;
      nv[j] = hcnt[i] + ((i >= off) ? hcnt[i-off] : 0);
    }
    __syncthreads();
    #pragma unroll
    for (int j = 0; j < 4; j++) hcnt[t + j*256] = nv[j];
    __syncthreads();
  }
  // inclusive -> exclusive
  #pragma unroll
  for (int j = 0; j < 4; j++) hcnt[t + j*256] -= own[j];
  __syncthreads();

  // emit bucket-offset row (hcnt[782] == cnt since buckets >=782 are empty)
  for (int i = t; i < 783; i += 256) hoffC[c*783 + i] = hcnt[i];

  // place edges bucket-major in LDS
  #pragma unroll
  for (int j = 0; j < 8; j++)
    if (b_[j] >= 0) simg[hcnt[b_[j]] + r_[j]] = v_[j];
  __syncthreads();

  // coalesced stream-out of the sorted chunk image
  for (int i = t; i < cnt; i += 256) binned[e0 + i] = simg[i];
}

// pass 2: WG per bucket gathers its segments from every chunk image and writes
// its own csr region (single-writer, full-line writebacks).  Per-node order
// resolved with LDS cursors.
__global__ __launch_bounds__(256) void k_gather(
    const int* __restrict__ binned, const int* __restrict__ hoffC,
    const int* __restrict__ row_ptr,
    int* __restrict__ csr, int N, int NC){
  __shared__ int lcur[128];
  int b = blockIdx.x, t = threadIdx.x;
  int n0 = b << 7;
  int nn = N - n0; if (nn > 128) nn = 128;
  if (t < nn) lcur[t] = row_ptr[n0 + t];
  __syncthreads();
  for (int c = t; c < NC; c += 256){
    int o0 = hoffC[c*783 + b];
    int o1 = hoffC[c*783 + b + 1];
    int base = c*CHUNK;
    for (int k = o0; k < o1; k++){
      int v = binned[base + k];
      int pos = atomicAdd(&lcur[v & 127], 1);
      csr[pos] = v >> 7;
    }
  }
}

// layer-1 aggregation over xs (9 features): thread per (node, feature), unroll-4 MLP
__global__ void k_agg9(const float* __restrict__ xs, const float* __restrict__ dis,
                       const int* __restrict__ row_ptr, const int* __restrict__ csr,
                       float* __restrict__ xagg, int N){
  int tid = blockIdx.x*blockDim.x + threadIdx.x;
  if (tid >= N*9) return;
  int n = tid/9, f = tid - n*9;
  float dn = dis[n];
  int s0 = row_ptr[n], s1 = row_ptr[n+1];
  float a0 = xs[tid];                 // self-loop term (x[n]*dis[n])
  float a1 = 0.f, a2 = 0.f, a3 = 0.f;
  int j = s0;
  for (; j + 3 < s1; j += 4){
    int e0 = csr[j], e1 = csr[j+1], e2 = csr[j+2], e3 = csr[j+3];
    a0 += xs[e0*9+f];
    a1 += xs[e1*9+f];
    a2 += xs[e2*9+f];
    a3 += xs[e3*9+f];
  }
  for (; j < s1; j++) a0 += xs[csr[j]*9+f];
  xagg[tid] = ((a0+a1)+(a2+a3))*dn;
}

// MFMA epilogue shared by the fused kernels.  hlw = this wave's 16x72-half
// LDS tile (row i = node wid + i*nwaves, cols 0..63 = dis*h fp16, 64..71 pad).
// Computes m' = (dis*h) @ Wn via D = A.B with A = Wn^T frags, B = h^T:
//   A[i][k]: lane(lm,lk) reg j -> Wn[(kb*32+lk*8+j)*64 + ft*16 + lm]
//   B[k][c]: lane(lm,lk) reg j -> hl[c=lm][kb*32+lk*8+j]  (ds_read_b128)
//   D[i][c]: lane(lm,lk) reg j -> m'[node lm][ft*16 + lk*4 + j]  (8B store)
__device__ __forceinline__ void mfma_epilogue(
    const _Float16* hlw, const f16x8 (&wf)[4][2],
    __half* __restrict__ mo, int wid, int nwaves, int N, int lane){
  int lm = lane & 15, lk = lane >> 4;
  f16x8 hb0 = *(const f16x8*)(hlw + lm*72 + lk*8);
  f16x8 hb1 = *(const f16x8*)(hlw + lm*72 + 32 + lk*8);
  int node = wid + lm*nwaves;
  bool ok = (node < N);
  __half* row = mo + (size_t)node*64;
  #pragma unroll
  for (int ft = 0; ft < 4; ft++){
    f32x4 acc = {0.f, 0.f, 0.f, 0.f};
    acc = __builtin_amdgcn_mfma_f32_16x16x32_f16(wf[ft][0], hb0, acc, 0, 0, 0);
    acc = __builtin_amdgcn_mfma_f32_16x16x32_f16(wf[ft][1], hb1, acc, 0, 0, 0);
    if (ok){
      h4v o;
      o.a = __floats2half2_rn(acc[0], acc[1]);
      o.b = __floats2half2_rn(acc[2], acc[3]);
      *(h4v*)(row + ft*16 + lk*4) = o;
    }
  }
}

#define LOAD_WFRAGS(Wn)                                                    \
  f16x8 wf[4][2];                                                          \
  { int lm_ = lane & 15, lk_ = lane >> 4;                                  \
    _Pragma("unroll") for (int ft = 0; ft < 4; ft++)                       \
    _Pragma("unroll") for (int kb = 0; kb < 2; kb++)                       \
    _Pragma("unroll") for (int j = 0; j < 8; j++)                          \
      wf[ft][kb][j] = (_Float16)Wn[(kb*32 + lk_*8 + j)*64 + ft*16 + lm_]; }

// layer 1 transform fused with next-layer message build:
// h1 = relu(xagg@W1+b1); m2 = fp16((dis*h1) @ W2).  h1 never stored.
__global__ __launch_bounds__(256) void k_lin1_fused(
    const float* __restrict__ xagg, const float* __restrict__ W1,
    const float* __restrict__ b1, const float* __restrict__ dis,
    const float* __restrict__ W2, __half* __restrict__ mo, int N, int nwaves){
  __shared__ float W1l[576];
  __shared__ float b1l[64];
  __shared__ _Float16 hl[4][16*72];
  int t = threadIdx.x;
  for (int i = t; i < 576; i += 256) W1l[i] = W1[i];
  if (t < 64) b1l[t] = b1[t];
  __syncthreads();
  int lane = t & 63, w = t >> 6;
  int wid = (blockIdx.x*blockDim.x + t) >> 6;
  LOAD_WFRAGS(W2)
  _Float16* hlw = hl[w];
  for (int i = 0; i < 16; i++){
    int n = wid + i*nwaves;
    _Float16 hv = (_Float16)0.f;
    if (n < N){
      float acc = b1l[lane];
      #pragma unroll
      for (int k = 0; k < 9; k++) acc = fmaf(xagg[n*9+k], W1l[k*64+lane], acc);
      hv = (_Float16)(fmaxf(acc, 0.f) * dis[n]);
    }
    hlw[i*72 + lane] = hv;
  }
  mfma_epilogue(hlw, wf, mo, wid, nwaves, N, lane);
}

// NOTE: param is g_ (NOT `a`): body reads members .a/.b/.c/.d and the
// preprocessor would substitute a same-named parameter into member tokens.
#define ACC8(g_)  do{ float2 t_;                                   \
  t_ = __half22float2((g_).a); acc0 += t_.x; acc1 += t_.y;         \
  t_ = __half22float2((g_).b); acc2 += t_.x; acc3 += t_.y;         \
  t_ = __half22float2((g_).c); acc4 += t_.x; acc5 += t_.y;         \
  t_ = __half22float2((g_).d); acc6 += t_.x; acc7 += t_.y; }while(0)

#define RED3(v)  do{ v += __shfl_xor(v, 8,64);                     \
                     v += __shfl_xor(v,16,64);                     \
                     v += __shfl_xor(v,32,64); }while(0)

// --- pipeline stages (named register sets; no runtime-indexed arrays) ---
// ISSUE: prefetch row_ptr 2 ahead, load self row + dis, csr indices, and
// launch the node's 16 gathers.  REDUCE (next half-step) consumes them.
#define AGG_ISSUE(n_, rp0_, rp1_, rn0_, rn1_, e0_, e1_, g0_, g1_, sf_, dn_) \
  do{                                                                      \
    int nn_ = (n_) + 2*nwaves;                                             \
    rn0_ = 0; rn1_ = 0;                                                    \
    if (nn_ < N){ rn0_ = row_ptr[nn_]; rn1_ = row_ptr[nn_+1]; }            \
    e0_ = -1; e1_ = -1;                                                    \
    if ((n_) < N){                                                         \
      sf_ = m[(size_t)(n_)*8 + q2];                                        \
      dn_ = dis[n_];                                                       \
      int j0_ = (rp0_) + sub, j1_ = (rp0_) + 8 + sub;                      \
      if (j0_ < (rp1_)) e0_ = csr[j0_];                                    \
      if (j1_ < (rp1_)) e1_ = csr[j1_];                                    \
      if (e0_ >= 0) g0_ = m[(size_t)e0_*8 + q2];                           \
      if (e1_ >= 0) g1_ = m[(size_t)e1_*8 + q2];                           \
    }                                                                      \
  }while(0)

#define AGG_ACCRED(n_, rp0_, rp1_, e0_, e1_, g0_, g1_, sf_, dn_)           \
      float acc0=0.f,acc1=0.f,acc2=0.f,acc3=0.f;                           \
      float acc4=0.f,acc5=0.f,acc6=0.f,acc7=0.f;                           \
      if (e0_ >= 0) ACC8(g0_);                                             \
      if (e1_ >= 0) ACC8(g1_);                                             \
      for (int j_ = (rp0_) + 16 + sub; j_ < (rp1_); j_ += 8){              \
        h8v gx_ = m[(size_t)csr[j_]*8 + q2]; ACC8(gx_);                    \
      }                                                                    \
      RED3(acc0); RED3(acc1); RED3(acc2); RED3(acc3);                      \
      RED3(acc4); RED3(acc5); RED3(acc6); RED3(acc7);                      \
      float2 s01=__half22float2((sf_).a), s23=__half22float2((sf_).b);     \
      float2 s45=__half22float2((sf_).c), s67=__half22float2((sf_).d);     \
      float r0 = fmaxf(fmaf(acc0 + s01.x, dn_, bb0.x), 0.f);               \
      float r1 = fmaxf(fmaf(acc1 + s01.y, dn_, bb0.y), 0.f);               \
      float r2 = fmaxf(fmaf(acc2 + s23.x, dn_, bb0.z), 0.f);               \
      float r3 = fmaxf(fmaf(acc3 + s23.y, dn_, bb0.w), 0.f);               \
      float r4 = fmaxf(fmaf(acc4 + s45.x, dn_, bb1.x), 0.f);               \
      float r5 = fmaxf(fmaf(acc5 + s45.y, dn_, bb1.y), 0.f);               \
      float r6 = fmaxf(fmaf(acc6 + s67.x, dn_, bb1.z), 0.f);               \
      float r7 = fmaxf(fmaf(acc7 + s67.y, dn_, bb1.w), 0.f);

// REDUCE for the fused kernels: writes fp16(dn*h) into the wave's LDS tile
#define AGG_REDUCE(n_, rp0_, rp1_, e0_, e1_, g0_, g1_, sf_, dn_, i_)       \
  do{                                                                      \
    if ((n_) < N){                                                         \
      AGG_ACCRED(n_, rp0_, rp1_, e0_, e1_, g0_, g1_, sf_, dn_)             \
      if (sub == 0){                                                       \
        h8v hv_;                                                           \
        hv_.a = __floats2half2_rn(r0*(dn_), r1*(dn_));                     \
        hv_.b = __floats2half2_rn(r2*(dn_), r3*(dn_));                     \
        hv_.c = __floats2half2_rn(r4*(dn_), r5*(dn_));                     \
        hv_.d = __floats2half2_rn(r6*(dn_), r7*(dn_));                     \
        *(h8v*)(hlw + (i_)*72 + q2*8) = hv_;                               \
      }                                                                    \
    } else if (sub == 0){                                                  \
      h8v z_; z_.a = __floats2half2_rn(0.f, 0.f);                          \
      z_.b = z_.a; z_.c = z_.a; z_.d = z_.a;                               \
      *(h8v*)(hlw + (i_)*72 + q2*8) = z_;                                  \
    }                                                                      \
  }while(0)

// layers 2,3: pipelined gather + fused next-layer transform.
__global__ __launch_bounds__(256) void k_agg_fused(
    const h8v* __restrict__ m, const float* __restrict__ dis,
    const float* __restrict__ b, const float* __restrict__ Wn,
    const int* __restrict__ row_ptr, const int* __restrict__ csr,
    __half* __restrict__ mo, int N, int nwaves){
  __shared__ _Float16 hl[4][16*72];
  int t = threadIdx.x;
  int lane = t & 63, w = t >> 6;
  int sub = lane >> 3, q2 = lane & 7;
  int wid = (blockIdx.x*blockDim.x + t) >> 6;
  _Float16* hlw = hl[w];
  const float4* b4 = (const float4*)b;
  float4 bb0 = b4[q2*2], bb1 = b4[q2*2+1];

  int nA = wid,          rA0 = 0, rA1 = 0;
  int nB = wid + nwaves, rB0 = 0, rB1 = 0;
  if (nA < N){ rA0 = row_ptr[nA]; rA1 = row_ptr[nA+1]; }
  if (nB < N){ rB0 = row_ptr[nB]; rB1 = row_ptr[nB+1]; }
  int eA0, eA1, eB0, eB1, rnA0, rnA1, rnB0, rnB1;
  h8v gA0, gA1, sfA, gB0, gB1, sfB;
  float dnA = 0.f, dnB = 0.f;
  AGG_ISSUE(nA, rA0, rA1, rnA0, rnA1, eA0, eA1, gA0, gA1, sfA, dnA);
  for (int p = 0; p < 8; p++){
    AGG_ISSUE(nB, rB0, rB1, rnB0, rnB1, eB0, eB1, gB0, gB1, sfB, dnB);
    AGG_REDUCE(nA, rA0, rA1, eA0, eA1, gA0, gA1, sfA, dnA, 2*p);
    nA += 2*nwaves; rA0 = rnA0; rA1 = rnA1;
    if (p < 7)
      AGG_ISSUE(nA, rA0, rA1, rnA0, rnA1, eA0, eA1, gA0, gA1, sfA, dnA);
    AGG_REDUCE(nB, rB0, rB1, eB0, eB1, gB0, gB1, sfB, dnB, 2*p+1);
    nB += 2*nwaves; rB0 = rnB0; rB1 = rnB1;
  }
  LOAD_WFRAGS(Wn)            // loaded at epilogue: not live during main loop
  mfma_epilogue(hlw, wf, mo, wid, nwaves, N, lane);
}

// layer 4 (R8's measured-60us while-loop form, reverted from the R11
// pipeline which regressed it to 70us): aggregation fused with output
// projection: per-node dot(h4, Wout) -> wave reduce -> atomic segment add.
__global__ __launch_bounds__(256) void k_agg64_out(
    const h8v* __restrict__ m, const float* __restrict__ dis,
    const float* __restrict__ b, const float* __restrict__ Wout,
    const int* __restrict__ batch,
    const int* __restrict__ row_ptr, const int* __restrict__ csr,
    float* gsum, int N, int nwaves){
  int lane = threadIdx.x & 63;
  int sub = lane >> 3, q2 = lane & 7;
  int n = (blockIdx.x*blockDim.x + threadIdx.x) >> 6;
  if (n >= N) return;
  int rp0 = row_ptr[n], rp1 = row_ptr[n+1];
  const float4* b4 = (const float4*)b;
  const float4* wo4 = (const float4*)Wout;
  while (true){
    int nn = n + nwaves;
    int np0 = 0, np1 = 0;
    if (nn < N){ np0 = row_ptr[nn]; np1 = row_ptr[nn+1]; }   // prefetch (indep)
    h8v sf = m[(size_t)n*8 + q2];                            // self row (indep)
    float dn = dis[n];
    int bg = batch[n];
    float acc0=0.f,acc1=0.f,acc2=0.f,acc3=0.f,acc4=0.f,acc5=0.f,acc6=0.f,acc7=0.f;
    int s1 = rp1;
    int j0 = rp0 + sub, j1 = rp0 + 8 + sub;
    if (j0 < s1){ h8v a = m[(size_t)csr[j0]*8 + q2]; ACC8(a); }
    if (j1 < s1){ h8v a = m[(size_t)csr[j1]*8 + q2]; ACC8(a); }
    for (int j = rp0 + 16 + sub; j < s1; j += 8){            // rare (deg>16)
      h8v a = m[(size_t)csr[j]*8 + q2]; ACC8(a);
    }
    RED3(acc0); RED3(acc1); RED3(acc2); RED3(acc3);
    RED3(acc4); RED3(acc5); RED3(acc6); RED3(acc7);
    float2 s01 = __half22float2(sf.a), s23 = __half22float2(sf.b);
    float2 s45 = __half22float2(sf.c), s67 = __half22float2(sf.d);
    float4 bb0 = b4[q2*2], bb1 = b4[q2*2+1];
    float4 w0 = wo4[q2*2], w1 = wo4[q2*2+1];
    float r0 = fmaxf(fmaf(acc0 + s01.x, dn, bb0.x), 0.f);
    float r1 = fmaxf(fmaf(acc1 + s01.y, dn, bb0.y), 0.f);
    float r2 = fmaxf(fmaf(acc2 + s23.x, dn, bb0.z), 0.f);
    float r3 = fmaxf(fmaf(acc3 + s23.y, dn, bb0.w), 0.f);
    float r4 = fmaxf(fmaf(acc4 + s45.x, dn, bb1.x), 0.f);
    float r5 = fmaxf(fmaf(acc5 + s45.y, dn, bb1.y), 0.f);
    float r6 = fmaxf(fmaf(acc6 + s67.x, dn, bb1.z), 0.f);
    float r7 = fmaxf(fmaf(acc7 + s67.y, dn, bb1.w), 0.f);
    float p = r0*w0.x + r1*w0.y + r2*w0.z + r3*w0.w
            + r4*w1.x + r5*w1.y + r6*w1.z + r7*w1.w;
    p += __shfl_xor(p,1,64); p += __shfl_xor(p,2,64); p += __shfl_xor(p,4,64);
    if (lane == 0) atomicAdd(&gsum[bg], p);
    if (nn >= N) break;
    n = nn; rp0 = np0; rp1 = np1;
  }
}

__global__ void k_final(const float* __restrict__ gsum, const int* __restrict__ gcount,
                        const float* __restrict__ bout, float* __restrict__ out, int G){
  int g = blockIdx.x*blockDim.x + threadIdx.x;
  if (g < G){
    int c = gcount[g];
    out[g] = gsum[g]/(float)(c > 0 ? c : 1) + bout[0];
  }
}

extern "C" void kernel_launch(void* const* d_in, const int* in_sizes, int n_in,
                              void* d_out, int out_size, void* d_ws, size_t ws_size,
                              hipStream_t stream){
  const float* x    = (const float*)d_in[0];
  const int*   ei   = (const int*)d_in[1];
  const int*   batch= (const int*)d_in[2];
  const float* W1 = (const float*)d_in[3];  const float* b1 = (const float*)d_in[4];
  const float* W2 = (const float*)d_in[5];  const float* b2 = (const float*)d_in[6];
  const float* W3 = (const float*)d_in[7];  const float* b3 = (const float*)d_in[8];
  const float* W4 = (const float*)d_in[9];  const float* b4 = (const float*)d_in[10];
  const float* Wout = (const float*)d_in[11]; const float* bout = (const float*)d_in[12];
  float* out = (float*)d_out;

  const int N = in_sizes[0]/9;
  const int E = in_sizes[1]/2;
  const int G = out_size;
  const int* src = ei;        // edge_index[0]
  const int* dst = ei + E;    // edge_index[1]

  char* ws = (char*)d_ws;
  size_t off = 0;
  auto alloc = [&](size_t bytes){ void* p = ws + off; off = align256(off + bytes); return p; };
  int*   deg      = (int*)  alloc((size_t)N*4);
  int*   row_ptr  = (int*)  alloc((size_t)(N+1)*4);
  int*   csr      = (int*)  alloc((size_t)E*4);
  float* dis      = (float*)alloc((size_t)N*4);
  const int NB  = (N + 255)/256;        // 391 (< 512 required by k_scanB)
  const int NBK = (N + 127)/128;        // 782 buckets of 128 dst nodes
  const int NC  = (E + CHUNK-1)/CHUNK;  // 489 sort chunks
  int*   blockSums= (int*)  alloc((size_t)NB*4);
  int*   blockOffs= (int*)  alloc((size_t)NB*4);
  int*   hoffC    = (int*)  alloc((size_t)NC*783*4);   // per-chunk bucket offsets
  float* gsum     = (float*)alloc((size_t)G*4);
  int*   gcount   = (int*)  alloc((size_t)G*4);
  __half* mA      = (__half*)alloc((size_t)N*64*2);  // fp16 message ping
  __half* mB      = (__half*)alloc((size_t)N*64*2);  // fp16 message pong
  // aliases (lifetimes verified):
  int*   binned   = (int*)mA;              // 4MB <= 12.8MB; dead after k_gather
  float* xs       = (float*)mB;            // 3.6MB; written by scanC, dead after agg9
  float* xagg     = xs + (size_t)N*9;      // 3.6MB; dead after k_lin1_fused
  // m2 = mA (written by lin1_fused, after binned dead)
  // m3 = mB (written by aggF layer2, after xs/xagg dead)
  // m4 = mA (written by aggF layer3, after m2 dead)

  const int EN = (E > N) ? E : N;
  const int AGG_BLOCKS = 2048;             // persistent: 8 blocks/CU on 256 CUs
  const int AGG_WAVES  = AGG_BLOCKS*4;     // 8192 waves; 16*8192 >= N (batch=16)

  k_zero     <<<(N+255)/256, 256, 0, stream>>>(deg, gsum, gcount, N, G);
  k_deg      <<<(EN+255)/256, 256, 0, stream>>>(dst, batch, deg, gcount, E, N);
  k_scanA    <<<NB, 256, 0, stream>>>(deg, blockSums, N);
  k_scanB    <<<1, 512, 0, stream>>>(blockSums, blockOffs, NB);
  k_scanC    <<<NB, 256, 0, stream>>>(deg, blockOffs, x, row_ptr, dis, xs, N);
  k_sortchunk<<<NC, 256, 0, stream>>>(src, dst, binned, hoffC, E);
  k_gather   <<<NBK, 256, 0, stream>>>(binned, hoffC, row_ptr, csr, N, NC);

  // layer 1: aggregate (9 feats, xs premultiplied in scanC), transform fused
  k_agg9  <<<(N*9+255)/256, 256, 0, stream>>>(xs, dis, row_ptr, csr, xagg, N);
  k_lin1_fused<<<AGG_BLOCKS, 256, 0, stream>>>(xagg, W1, b1, dis, W2, mA, N, AGG_WAVES);

  // layer 2: aggregate m2 -> h2 (regs) -> m3   (uses b2, W3)
  k_agg_fused<<<AGG_BLOCKS, 256, 0, stream>>>((const h8v*)mA, dis, b2, W3,
                                              row_ptr, csr, mB, N, AGG_WAVES);
  // layer 3: aggregate m3 -> h3 (regs) -> m4   (uses b3, W4)
  k_agg_fused<<<AGG_BLOCKS, 256, 0, stream>>>((const h8v*)mB, dis, b3, W4,
                                              row_ptr, csr, mA, N, AGG_WAVES);
  // layer 4: aggregate m4 -> h4 (regs) -> Wout dot -> pooled sums
  k_agg64_out<<<AGG_BLOCKS, 256, 0, stream>>>((const h8v*)mA, dis, b4, Wout, batch,
                                              row_ptr, csr, gsum, N, AGG_WAVES);

  k_final<<<(G+255)/256, 256, 0, stream>>>(gsum, gcount, bout, out, G);
}